// Round 12
// baseline (526.281 us; speedup 1.0000x reference)
//
#include <hip/hip_runtime.h>
#include <hip/hip_bf16.h>

#define NNODES 50000
#define NEDGES 800000
#define NP 50048            // 391 * 128 = 1564 * 32, padded node count
#define DIM 128
#define HEADS 8
#define FFNDIM 512

typedef __bf16 bf16x8 __attribute__((ext_vector_type(8)));
typedef float f32x4 __attribute__((ext_vector_type(4)));
typedef unsigned int uint32;
typedef unsigned short ushort16;

__device__ __forceinline__ float b2f(uint32 u) {
  union { uint32 i; float f; } x; x.i = u << 16; return x.f;
}
__device__ __forceinline__ float b2fh(uint32 u) {   // high half, no shift needed
  union { uint32 i; float f; } x; x.i = u & 0xffff0000u; return x.f;
}
__device__ __forceinline__ ushort16 f2b(float f) {
  __bf16 h = (__bf16)f; return __builtin_bit_cast(ushort16, h);
}
__device__ __forceinline__ float h2f(unsigned short u) {
  return (float)__builtin_bit_cast(_Float16, u);
}
__device__ __forceinline__ unsigned short f2h(float f) {
  return __builtin_bit_cast(unsigned short, (_Float16)f);
}

// ---------------- embed (blocks 0..1562, 8 threads/node) + partitioned hist (4096 blocks) ----------------
__global__ void k_embed_hist(const int* __restrict__ ent_ids, const int* __restrict__ arw_pos,
                             const float* __restrict__ ent_tab, const float* __restrict__ pos_tab,
                             __bf16* __restrict__ hb, const int* __restrict__ dst,
                             int* __restrict__ deg) {
  int bid = blockIdx.x, tid = threadIdx.x;
  if (bid < 1563) {
    int t = bid * 256 + tid;            // over N*8 (1563*256 = 400128 >= 400000)
    if (t < NNODES * 8) {
      int n = t >> 3, c = t & 7;
      int e = ent_ids[n], a2 = arw_pos[n];
      #pragma unroll
      for (int i = 0; i < 4; ++i) {
        float4 a0 = ((const float4*)ent_tab)[e * 32 + c * 4 + i];
        float4 b0 = ((const float4*)pos_tab)[a2 * 32 + c * 4 + i];
        ushort4 o;
        o.x = f2b(a0.x + b0.x); o.y = f2b(a0.y + b0.y);
        o.z = f2b(a0.z + b0.z); o.w = f2b(a0.w + b0.w);
        ((ushort4*)hb)[n * 32 + c * 4 + i] = o;
      }
    }
  } else {
    int hbid = bid - 1563;              // 0..4095
    int part = hbid & 7;
    int lo = part * 6250, hi2 = lo + 6250;
    for (int e = (hbid >> 3) * 256 + tid; e < NEDGES; e += 512 * 256) {
      int d = dst[e];
      if (d >= lo && d < hi2) atomicAdd(&deg[d], 1);
    }
  }
}

// ---------------- prepA: blocks 0..48 chunk sums; 49..52 relsc; 53..340 transpose ----------------
__global__ void k_prepA(const int* __restrict__ deg, int* __restrict__ csum,
                        const float* __restrict__ Wr, const float* __restrict__ ar,
                        const float* __restrict__ rel_tab, float* __restrict__ relsc,
                        const float* __restrict__ Wh0, const float* __restrict__ Wh1,
                        const float* __restrict__ w10, const float* __restrict__ w11,
                        const float* __restrict__ w20, const float* __restrict__ w21,
                        __bf16* __restrict__ T0, __bf16* __restrict__ T1,
                        __bf16* __restrict__ T2, __bf16* __restrict__ T3,
                        __bf16* __restrict__ T4, __bf16* __restrict__ T5) {
  int bid = blockIdx.x, tid = threadIdx.x;
  if (bid < 49) {
    __shared__ int ws[16];
    int lane = tid & 63, w = tid >> 6;
    int i = bid * 1024 + tid;
    int v = (i < NNODES) ? deg[i] : 0;
    #pragma unroll
    for (int o = 1; o < 64; o <<= 1) v += __shfl_xor(v, o);
    if (lane == 0) ws[w] = v;
    __syncthreads();
    if (tid == 0) {
      int s = 0;
      #pragma unroll
      for (int k = 0; k < 16; ++k) s += ws[k];
      csum[bid] = s;
    }
  } else if (bid <= 52) {
    __shared__ float vr[1024];
    int d = tid >> 3, hh = tid & 7;
    float s = 0.f;
    #pragma unroll
    for (int k = 0; k < 16; ++k) s += Wr[d * 128 + hh * 16 + k] * ar[hh * 16 + k];
    vr[tid] = s;
    __syncthreads();
    int t = (bid - 49) * 1024 + tid;
    if (t < 500 * 8) {
      int r = t >> 3, h2 = t & 7;
      float acc = 0.f;
      for (int dd = 0; dd < 128; ++dd) acc += rel_tab[r * 128 + dd] * vr[dd * 8 + h2];
      relsc[t] = acc;
    }
  } else {
    // transpose+convert, coalesced WRITES
    int wb = bid - 53;
    const float* W; __bf16* T; int lr2, lc2;
    int sub;
    if (wb < 16)        { W = Wh0; T = T0; lr2 = 7; lc2 = 7; sub = wb; }
    else if (wb < 32)   { W = Wh1; T = T1; lr2 = 7; lc2 = 7; sub = wb - 16; }
    else if (wb < 96)   { W = w10; T = T2; lr2 = 7; lc2 = 9; sub = wb - 32; }
    else if (wb < 160)  { W = w11; T = T3; lr2 = 7; lc2 = 9; sub = wb - 96; }
    else if (wb < 224)  { W = w20; T = T4; lr2 = 9; lc2 = 7; sub = wb - 160; }
    else                { W = w21; T = T5; lr2 = 9; lc2 = 7; sub = wb - 224; }
    int idx = sub * 1024 + tid;
    int r = idx & ((1 << lr2) - 1);
    int c = idx >> lr2;
    T[((long)c << lr2) + r] = (__bf16)W[((long)r << lc2) + c];
  }
}

// ---------------- prepC: per-chunk local scan + inline csum scan (49 blocks x 1024) ----------------
__global__ void k_prepC(const int* __restrict__ deg, const int* __restrict__ csum,
                        int* __restrict__ rowptr, int* __restrict__ cursor) {
  __shared__ int wsum[16];
  __shared__ int s_coff, s_tot;
  int tid = threadIdx.x, lane = tid & 63, w = tid >> 6;
  if (tid < 64) {
    int v = (tid < 49) ? csum[tid] : 0;
    int x = v;
    #pragma unroll
    for (int o = 1; o < 64; o <<= 1) {
      int t = __shfl_up(x, o);
      if (tid >= o) x += t;
    }
    if (tid == (int)blockIdx.x) s_coff = x - v;
    if (tid == 48) s_tot = x;
  }
  int i = blockIdx.x * 1024 + tid;
  int v = (i < NNODES) ? deg[i] : 0;
  int x = v;
  #pragma unroll
  for (int o = 1; o < 64; o <<= 1) {
    int t = __shfl_up(x, o);
    if (lane >= o) x += t;
  }
  if (lane == 63) wsum[w] = x;
  __syncthreads();
  if (w == 0 && lane < 16) {
    int t = wsum[lane];
    #pragma unroll
    for (int o = 1; o < 16; o <<= 1) {
      int u = __shfl_up(t, o);
      if (lane >= o) t += u;
    }
    wsum[lane] = t;
  }
  __syncthreads();
  int add = s_coff + (w > 0 ? wsum[w - 1] : 0);
  if (i < NNODES) { rowptr[i] = add + x - v; cursor[i] = add + x - v; }
  if (blockIdx.x == 0 && tid == 0) rowptr[NNODES] = s_tot;
}

// ---------------- partitioned scatter: pack (src<<6)|(rel<<22) into CSR slots ----------------
__global__ __launch_bounds__(256) void k_scatter(
    const int* __restrict__ dst, const int* __restrict__ src,
    const int* __restrict__ rel_ids, int* __restrict__ cursor,
    uint32* __restrict__ packed) {
  int part = blockIdx.x & 7;
  int lo = part * 6250, hi2 = lo + 6250;
  int tid = threadIdx.x;
  for (int e = (int)(blockIdx.x >> 3) * 256 + tid; e < NEDGES; e += 256 * 256) {
    int d = dst[e];
    if (d >= lo && d < hi2) {
      int p = atomicAdd(&cursor[d], 1);
      packed[p] = ((uint32)src[e] << 6) | ((uint32)rel_ids[e] << 22);
    }
  }
}

// ---------------- fused: f = hb@Wht (MFMA) + attention-scores epilogue ----------------
__global__ __launch_bounds__(256) void k_gemm0s(
    const __bf16* __restrict__ A, const __bf16* __restrict__ Bt,
    __bf16* __restrict__ fout, const float* __restrict__ ah, const float* __restrict__ at,
    float* __restrict__ ssrc, float* __restrict__ sdst) {
  __shared__ char sA[16384];   // 128 rows x 64 bf16, XOR-swizzled
  __shared__ char sB[16384];
  const int tid = threadIdx.x;
  const int lane = tid & 63, wid = tid >> 6;
  const int wr = wid >> 1, wc = wid & 1;
  const int lr = lane & 15, hi = lane >> 4;
  const long row0 = (long)blockIdx.x * 128;
  f32x4 acc[4][4] = {};

  for (int kc = 0; kc < 2; ++kc) {
    __syncthreads();
    #pragma unroll
    for (int i = 0; i < 4; ++i) {
      int q = i * 256 + tid;
      int r = q >> 3, slot = q & 7;
      int sw = ((slot ^ (r & 7)) << 4);
      int4 av = *(const int4*)(A + (row0 + r) * 128 + kc * 64 + slot * 8);
      *(int4*)(sA + r * 128 + sw) = av;
      int4 bv = *(const int4*)(Bt + (long)r * 128 + kc * 64 + slot * 8);
      *(int4*)(sB + r * 128 + sw) = bv;
    }
    __syncthreads();
    #pragma unroll
    for (int ks = 0; ks < 2; ++ks) {
      bf16x8 af[4], bfr[4];
      #pragma unroll
      for (int m = 0; m < 4; ++m) {
        int r = wr * 64 + m * 16 + lr;
        int cb = ((ks * 4 + hi) ^ (r & 7)) << 4;
        af[m] = *(const bf16x8*)(sA + r * 128 + cb);
      }
      #pragma unroll
      for (int n = 0; n < 4; ++n) {
        int r = wc * 64 + n * 16 + lr;
        int cb = ((ks * 4 + hi) ^ (r & 7)) << 4;
        bfr[n] = *(const bf16x8*)(sB + r * 128 + cb);
      }
      #pragma unroll
      for (int m = 0; m < 4; ++m)
        #pragma unroll
        for (int n = 0; n < 4; ++n)
          acc[m][n] = __builtin_amdgcn_mfma_f32_16x16x32_bf16(af[m], bfr[n], acc[m][n], 0, 0, 0);
    }
  }

  float ahr[4], atr[4];
  #pragma unroll
  for (int n = 0; n < 4; ++n) {
    ahr[n] = ah[(wc * 4 + n) * 16 + lr];
    atr[n] = at[(wc * 4 + n) * 16 + lr];
  }
  #pragma unroll
  for (int m = 0; m < 4; ++m) {
    #pragma unroll
    for (int j = 0; j < 4; ++j) {
      long r = row0 + wr * 64 + m * 16 + hi * 4 + j;
      #pragma unroll
      for (int n = 0; n < 4; ++n) {
        long c = wc * 64 + n * 16 + lr;
        float v = acc[m][n][j];
        fout[r * 128 + c] = (__bf16)v;
        float ps = v * ahr[n], pt = v * atr[n];
        #pragma unroll
        for (int o = 1; o < 16; o <<= 1) { ps += __shfl_xor(ps, o); pt += __shfl_xor(pt, o); }
        if (lr == 0) {
          ssrc[r * 8 + wc * 4 + n] = ps;
          sdst[r * 8 + wc * 4 + n] = pt;
        }
      }
    }
  }
}

// ---------------- fused FFN: out = LN(relu(ob@w1+c1)@w2 + c2 + ob) -- 32-row blocks ----------------
// phase1: T(32x512 bf16) into LDS (B=w1t read direct from L2, 128KB table, hot)
// phase2: V = T@w2t + c2 + resid(ob LDS tile); phase3: row LayerNorm
__global__ __launch_bounds__(256) void k_ffn(
    const __bf16* __restrict__ A, const __bf16* __restrict__ w1t, const float* __restrict__ c1,
    const __bf16* __restrict__ w2t, const float* __restrict__ c2,
    const float* __restrict__ g, const float* __restrict__ b,
    __bf16* __restrict__ outb, float* __restrict__ outf) {
  __shared__ char sO[8192];        // 32 x 128 bf16 (row stride 256B), XOR-swizzled
  __shared__ char sT[32768];       // 32 x 512 bf16 (row stride 1024B), XOR-swizzled
  __shared__ float sV[32 * 128];   // 16 KB fp32
  const int tid = threadIdx.x;
  const int lane = tid & 63, wid = tid >> 6;
  const int lr = lane & 15, hi = lane >> 4;
  const long row0 = (long)blockIdx.x * 32;

  // stage ob tile: 32 rows x 16 slots of 16B
  #pragma unroll
  for (int i = 0; i < 2; ++i) {
    int q = i * 256 + tid;
    int r = q >> 4, slot = q & 15;
    int4 v = *(const int4*)(A + (row0 + r) * 128 + slot * 8);
    *(int4*)(sO + r * 256 + ((slot ^ (r & 7)) << 4)) = v;
  }
  __syncthreads();

  // phase 1: wave wid computes T cols [wid*128, +128)
  {
    f32x4 acc[2][8] = {};
    #pragma unroll
    for (int ks = 0; ks < 4; ++ks) {
      bf16x8 af[2];
      #pragma unroll
      for (int m = 0; m < 2; ++m) {
        int r = m * 16 + lr;
        af[m] = *(const bf16x8*)(sO + r * 256 + (((ks * 4 + hi) ^ (r & 7)) << 4));
      }
      #pragma unroll
      for (int n = 0; n < 8; ++n) {
        long c = wid * 128 + n * 16 + lr;
        bf16x8 bf = *(const bf16x8*)(w1t + c * 128 + ks * 32 + hi * 8);
        #pragma unroll
        for (int m = 0; m < 2; ++m)
          acc[m][n] = __builtin_amdgcn_mfma_f32_16x16x32_bf16(af[m], bf, acc[m][n], 0, 0, 0);
      }
    }
    #pragma unroll
    for (int n = 0; n < 8; ++n) {
      int c = wid * 128 + n * 16 + lr;
      float bias = c1[c];
      #pragma unroll
      for (int m = 0; m < 2; ++m) {
        #pragma unroll
        for (int j = 0; j < 4; ++j) {
          int r = m * 16 + hi * 4 + j;
          float v = fmaxf(acc[m][n][j] + bias, 0.f);
          int byte = r * 1024 + ((((c >> 3) ^ (r & 7)) << 4)) + ((c * 2) & 15);
          *(__bf16*)(sT + byte) = (__bf16)v;
        }
      }
    }
  }
  __syncthreads();

  // phase 2: wave wid computes out cols [wid*32, +32), K=512
  {
    f32x4 acc[2][2] = {};
    #pragma unroll 4
    for (int ks = 0; ks < 16; ++ks) {
      bf16x8 af[2];
      #pragma unroll
      for (int m = 0; m < 2; ++m) {
        int r = m * 16 + lr;
        af[m] = *(const bf16x8*)(sT + r * 1024 + (((ks * 4 + hi) ^ (r & 7)) << 4));
      }
      #pragma unroll
      for (int n = 0; n < 2; ++n) {
        long c = wid * 32 + n * 16 + lr;
        bf16x8 bf = *(const bf16x8*)(w2t + c * 512 + ks * 32 + hi * 8);
        #pragma unroll
        for (int m = 0; m < 2; ++m)
          acc[m][n] = __builtin_amdgcn_mfma_f32_16x16x32_bf16(af[m], bf, acc[m][n], 0, 0, 0);
      }
    }
    #pragma unroll
    for (int n = 0; n < 2; ++n) {
      int c = wid * 32 + n * 16 + lr;
      float bias = c2[c];
      #pragma unroll
      for (int m = 0; m < 2; ++m) {
        #pragma unroll
        for (int j = 0; j < 4; ++j) {
          int r = m * 16 + hi * 4 + j;
          int ob_byte = r * 256 + ((((c >> 3) ^ (r & 7)) << 4)) + ((c * 2) & 15);
          float resid = (float)*(const __bf16*)(sO + ob_byte);
          sV[r * 128 + c] = acc[m][n][j] + bias + resid;
        }
      }
    }
  }
  __syncthreads();

  // phase 3: LayerNorm, wave wid handles rows wid*8 .. +7
  float2 gg = ((const float2*)g)[lane];
  float2 bb = ((const float2*)b)[lane];
  for (int rr = 0; rr < 8; ++rr) {
    int rloc = wid * 8 + rr;
    long r = row0 + rloc;
    float2 v = ((float2*)sV)[rloc * 64 + lane];
    float x = v.x, y = v.y;
    float s = x + y;
    #pragma unroll
    for (int o = 1; o < 64; o <<= 1) s += __shfl_xor(s, o);
    float mean = s * (1.f / 128.f);
    float dx = x - mean, dy = y - mean;
    float q = dx * dx + dy * dy;
    #pragma unroll
    for (int o = 1; o < 64; o <<= 1) q += __shfl_xor(q, o);
    float rs = rsqrtf(q * (1.f / 128.f) + 1e-5f);
    float ox = dx * rs * gg.x + bb.x;
    float oy = dy * rs * gg.y + bb.y;
    if (outf) ((float2*)outf)[r * 64 + lane] = make_float2(ox, oy);
    ((uint32*)outb)[r * 64 + lane] = ((uint32)f2b(oy) << 16) | (uint32)f2b(ox);
  }
}

// ---------------- edge softmax: register path (deg<=64), fallback 2-pass; fp16 att ----------------
__global__ void k_softmax(const int* __restrict__ rowptr, const uint32* __restrict__ packed,
                          const float* __restrict__ ssrc, const float* __restrict__ sdst,
                          const float* __restrict__ relsc, unsigned short* __restrict__ att16) {
  int lane = threadIdx.x & 63, wid = threadIdx.x >> 6;
  int n = blockIdx.x * 4 + wid;
  if (n >= NNODES) return;
  int start = rowptr[n], end = rowptr[n + 1];
  if (start == end) return;
  int hh = lane & 7, jj = lane >> 3;
  float sd = sdst[n * 8 + hh];
  float m = -1e30f, den = 0.f;
  int deg = end - start;

  if (deg <= 64) {
    uint32 pk[8];
    float ev[8];
    int end1 = end - 1;
    #pragma unroll
    for (int t = 0; t < 8; ++t)
      pk[t] = packed[min(start + t * 8 + jj, end1)];
    #pragma unroll
    for (int t = 0; t < 8; ++t)
      ev[t] = ssrc[((pk[t] & 0x3fffffu) >> 3) | (uint32)hh];    // src*8 + hh
    #pragma unroll
    for (int t = 0; t < 8; ++t) {
      int j = start + t * 8 + jj;
      float e = ev[t] + sd;
      if (relsc) e += relsc[((pk[t] >> 22) << 3) | (uint32)hh];
      e = (e >= 0.f) ? e : 0.2f * e;
      ev[t] = e;
      if (j < end) {
        float M = fmaxf(m, e);
        den = den * __expf(m - M) + __expf(e - M);
        m = M;
      }
    }
    #pragma unroll
    for (int o = 8; o < 64; o <<= 1) {
      float m2 = __shfl_xor(m, o), d2 = __shfl_xor(den, o);
      float M = fmaxf(m, m2);
      den = den * __expf(m - M) + d2 * __expf(m2 - M);
      m = M;
    }
    float inv = 1.f / (den + 1e-16f);
    #pragma unroll
    for (int t = 0; t < 8; ++t) {
      int j = start + t * 8 + jj;
      if (j < end) att16[j * 8 + hh] = f2h(__expf(ev[t] - m) * inv);
    }
  } else {
    for (int j0 = start; j0 < end; j0 += 8) {
      int j = j0 + jj;
      if (j < end) {
        uint32 p2 = packed[j];
        float e = ssrc[((p2 & 0x3fffffu) >> 3) | (uint32)hh] + sd;
        if (relsc) e += relsc[((p2 >> 22) << 3) | (uint32)hh];
        e = (e >= 0.f) ? e : 0.2f * e;
        att16[j * 8 + hh] = f2h(e);
        float M = fmaxf(m, e);
        den = den * __expf(m - M) + __expf(e - M);
        m = M;
      }
    }
    #pragma unroll
    for (int o = 8; o < 64; o <<= 1) {
      float m2 = __shfl_xor(m, o), d2 = __shfl_xor(den, o);
      float M = fmaxf(m, m2);
      den = den * __expf(m - M) + d2 * __expf(m2 - M);
      m = M;
    }
    float inv = 1.f / (den + 1e-16f);
    for (int j0 = start; j0 < end; j0 += 8) {
      int j = j0 + jj;
      if (j < end) att16[j * 8 + hh] = f2h(__expf(h2f(att16[j * 8 + hh]) - m) * inv);
    }
  }
}

// ---------------- diffusion hop: R10 structure, fp16 att direct loads ----------------
template<int FINAL>
__global__ __launch_bounds__(256) void k_hop(
    const int* __restrict__ rowptr, const uint32* __restrict__ packed,
    const unsigned short* __restrict__ att16, const __bf16* __restrict__ fin,
    const __bf16* __restrict__ f0, __bf16* __restrict__ fout,
    const __bf16* __restrict__ resid, const float* __restrict__ g,
    const float* __restrict__ b) {
  int lane = threadIdx.x & 63, wid = threadIdx.x >> 6;
  int n = blockIdx.x * 4 + wid;
  if (n >= NNODES) return;
  uint32 z = ((const uint32*)f0)[n * 64 + lane];
  uint32 rz = 0u;
  if (FINAL) rz = ((const uint32*)resid)[n * 64 + lane];
  int start = rowptr[n], end = rowptr[n + 1];
  int hsel = lane >> 3;
  float ax = 0.f, ay = 0.f;
  const uint32* fin2 = (const uint32*)fin;
  int deg = end - start;
  int nfull = deg >> 4;
  int j0 = start;
  for (int bb2 = 0; bb2 < nfull; ++bb2, j0 += 16) {   // full 16-edge batches, unmasked
    #pragma unroll
    for (int k = 0; k < 16; ++k) {
      float a = h2f(att16[(j0 + k) * 8 + hsel]);
      uint32 pk = packed[j0 + k];
      uint32 v = fin2[(pk & 0x3fffffu) | (uint32)lane];
      ax += a * b2f(v & 0xffffu);
      ay += a * b2fh(v);
    }
  }
  int nb = deg & 15;
  if (nb) {                                           // masked tail: 8 + optional 8
    int end1 = end - 1;
    #pragma unroll
    for (int k = 0; k < 8; ++k) {
      int jc = min(j0 + k, end1);
      float a = h2f(att16[jc * 8 + hsel]);
      a = (k < nb) ? a : 0.f;
      uint32 pk = packed[jc];
      uint32 v = fin2[(pk & 0x3fffffu) | (uint32)lane];
      ax += a * b2f(v & 0xffffu);
      ay += a * b2fh(v);
    }
    if (nb > 8) {
      #pragma unroll
      for (int k = 8; k < 16; ++k) {
        int jc = min(j0 + k, end1);
        float a = h2f(att16[jc * 8 + hsel]);
        a = (k < nb) ? a : 0.f;
        uint32 pk = packed[jc];
        uint32 v = fin2[(pk & 0x3fffffu) | (uint32)lane];
        ax += a * b2f(v & 0xffffu);
        ay += a * b2fh(v);
      }
    }
  }
  float ox = 0.15f * b2f(z & 0xffffu) + 0.85f * ax;
  float oy = 0.15f * b2fh(z) + 0.85f * ay;
  if (!FINAL) {
    ((uint32*)fout)[n * 64 + lane] = ((uint32)f2b(oy) << 16) | (uint32)f2b(ox);
  } else {
    float x = ox + b2f(rz & 0xffffu);
    float y = oy + b2fh(rz);
    float s = x + y;
    #pragma unroll
    for (int o = 1; o < 64; o <<= 1) s += __shfl_xor(s, o);
    float mean = s * (1.f / 128.f);
    float dx = x - mean, dy = y - mean;
    float q = dx * dx + dy * dy;
    #pragma unroll
    for (int o = 1; o < 64; o <<= 1) q += __shfl_xor(q, o);
    float rs2 = rsqrtf(q * (1.f / 128.f) + 1e-5f);
    float2 gg = ((const float2*)g)[lane];
    float2 bb = ((const float2*)b)[lane];
    float o1 = dx * rs2 * gg.x + bb.x;
    float o2 = dy * rs2 * gg.y + bb.y;
    ((uint32*)fout)[n * 64 + lane] = ((uint32)f2b(o2) << 16) | (uint32)f2b(o1);
  }
}

// ---------------- final gather (fp32) ----------------
__global__ void k_gather(const int* __restrict__ ids, const float* __restrict__ h,
                         float* __restrict__ out) {
  int t = blockIdx.x * 256 + threadIdx.x;   // 512*32
  if (t >= 512 * 32) return;
  int b = t >> 5, c = t & 31;
  ((float4*)out)[t] = ((const float4*)h)[(long)ids[b] * 32 + c];
}

// ---------------- host side ----------------
struct LayerW {
  const float *Wh, *ah, *at, *g1, *b1, *w1, *c1, *w2, *c2, *g2, *b2;
};

extern "C" void kernel_launch(void* const* d_in, const int* in_sizes, int n_in,
                              void* d_out, int out_size, void* d_ws, size_t ws_size,
                              hipStream_t stream) {
  const int* ent_ids   = (const int*)d_in[0];
  const int* rel_ids   = (const int*)d_in[1];
  const int* arw_pos   = (const int*)d_in[2];
  const int* src       = (const int*)d_in[3];
  const int* dst       = (const int*)d_in[4];
  const int* batch_ids = (const int*)d_in[5];
  const float* ent_tab = (const float*)d_in[6];
  const float* rel_tab = (const float*)d_in[7];
  const float* pos_tab = (const float*)d_in[8];

  LayerW L0 = {(const float*)d_in[9],  (const float*)d_in[11], (const float*)d_in[12],
               (const float*)d_in[14], (const float*)d_in[15], (const float*)d_in[16],
               (const float*)d_in[17], (const float*)d_in[18], (const float*)d_in[19],
               (const float*)d_in[20], (const float*)d_in[21]};
  const float* l0_Wr = (const float*)d_in[10];
  const float* l0_ar = (const float*)d_in[13];
  LayerW L1 = {(const float*)d_in[22], (const float*)d_in[23], (const float*)d_in[24],
               (const float*)d_in[25], (const float*)d_in[26], (const float*)d_in[27],
               (const float*)d_in[28], (const float*)d_in[29], (const float*)d_in[30],
               (const float*)d_in[31], (const float*)d_in[32]};

  // ---- workspace carve ----
  char* p = (char*)d_ws;
  auto alloc = [&](size_t bytes) { char* q = p; p += (bytes + 255) & ~(size_t)255; return q; };
  __bf16* hb = (__bf16*)alloc((size_t)NP * 128 * 2);
  __bf16* f  = (__bf16*)alloc((size_t)NP * 128 * 2);
  __bf16* fb = (__bf16*)alloc((size_t)NP * 128 * 2);   // must follow f (y aliases f+fb)
  __bf16* fa = (__bf16*)alloc((size_t)NP * 128 * 2);
  __bf16* ob = (__bf16*)alloc((size_t)NP * 128 * 2);
  unsigned short* att16 = (unsigned short*)alloc((size_t)NEDGES * 8 * 2);
  float*  y   = (float*)f;                             // fp32 NP*128, spans f+fb
  float* ssrc  = (float*)alloc((size_t)NP * 8 * 4);
  float* sdst  = (float*)alloc((size_t)NP * 8 * 4);
  float* relsc = (float*)alloc(500 * 8 * 4);
  __bf16* Wht0 = (__bf16*)alloc(128 * 128 * 2);
  __bf16* Wht1 = (__bf16*)alloc(128 * 128 * 2);
  __bf16* w1t0 = (__bf16*)alloc(512 * 128 * 2);
  __bf16* w1t1 = (__bf16*)alloc(512 * 128 * 2);
  __bf16* w2t0 = (__bf16*)alloc(128 * 512 * 2);
  __bf16* w2t1 = (__bf16*)alloc(128 * 512 * 2);
  int* deg    = (int*)alloc(NNODES * 4);
  int* rowptr = (int*)alloc((NNODES + 1) * 4);
  int* cursor = (int*)alloc(NNODES * 4);
  int* csum   = (int*)alloc(64 * 4);
  uint32* packed = (uint32*)alloc((size_t)NEDGES * 4);

  // zero pads of GEMM A-inputs + degree array
  hipMemsetAsync(hb + (size_t)NNODES * 128, 0, (size_t)(NP - NNODES) * 128 * 2, stream);
  hipMemsetAsync(ob + (size_t)NNODES * 128, 0, (size_t)(NP - NNODES) * 128 * 2, stream);
  hipMemsetAsync(deg, 0, NNODES * sizeof(int), stream);

  k_embed_hist<<<1563 + 4096, 256, 0, stream>>>(ent_ids, arw_pos, ent_tab, pos_tab, hb, dst, deg);
  k_prepA<<<341, 1024, 0, stream>>>(deg, csum, l0_Wr, l0_ar, rel_tab, relsc,
                                    L0.Wh, L1.Wh, L0.w1, L1.w1, L0.w2, L1.w2,
                                    Wht0, Wht1, w1t0, w1t1, w2t0, w2t1);
  k_prepC<<<49, 1024, 0, stream>>>(deg, csum, rowptr, cursor);
  k_scatter<<<2048, 256, 0, stream>>>(dst, src, rel_ids, cursor, packed);

  const int NB4 = (NNODES + 3) / 4;
  for (int L = 0; L < 2; ++L) {
    const LayerW& W = L ? L1 : L0;
    const __bf16* Wht = L ? Wht1 : Wht0;
    const __bf16* w1t = L ? w1t1 : w1t0;
    const __bf16* w2t = L ? w2t1 : w2t0;
    const float* rsc  = L ? nullptr : relsc;

    k_gemm0s<<<391, 256, 0, stream>>>(hb, Wht, f, W.ah, W.at, ssrc, sdst);
    k_softmax<<<NB4, 256, 0, stream>>>(rowptr, packed, ssrc, sdst, rsc, att16);
    k_hop<0><<<NB4, 256, 0, stream>>>(rowptr, packed, att16, f, f, fa, nullptr, nullptr, nullptr);
    k_hop<0><<<NB4, 256, 0, stream>>>(rowptr, packed, att16, fa, f, fb, nullptr, nullptr, nullptr);
    k_hop<1><<<NB4, 256, 0, stream>>>(rowptr, packed, att16, fb, f, ob, hb, W.g1, W.b1);
    k_ffn<<<NP / 32, 256, 0, stream>>>(ob, w1t, W.c1, w2t, W.c2, W.g2, W.b2, hb,
                                       (L == 1) ? y : nullptr);
  }

  k_gather<<<64, 256, 0, stream>>>(batch_ids, y, (float*)d_out);
}

// Round 13
// 497.360 us; speedup vs baseline: 1.0581x; 1.0581x over previous
//
#include <hip/hip_runtime.h>
#include <hip/hip_bf16.h>

#define NNODES 50000
#define NEDGES 800000
#define NP 50048            // 391 * 128, padded node count
#define DIM 128
#define HEADS 8
#define FFNDIM 512

typedef __bf16 bf16x8 __attribute__((ext_vector_type(8)));
typedef float f32x4 __attribute__((ext_vector_type(4)));
typedef unsigned int uint32;
typedef unsigned short ushort16;

__device__ __forceinline__ float b2f(uint32 u) {
  union { uint32 i; float f; } x; x.i = u << 16; return x.f;
}
__device__ __forceinline__ float b2fh(uint32 u) {   // high half, no shift needed
  union { uint32 i; float f; } x; x.i = u & 0xffff0000u; return x.f;
}
__device__ __forceinline__ ushort16 f2b(float f) {
  __bf16 h = (__bf16)f; return __builtin_bit_cast(ushort16, h);
}
__device__ __forceinline__ float h2f(unsigned short u) {
  return (float)__builtin_bit_cast(_Float16, u);
}
__device__ __forceinline__ unsigned short f2h(float f) {
  return __builtin_bit_cast(unsigned short, (_Float16)f);
}

// ---------------- embed (blocks 0..1562, 8 threads/node) + partitioned hist (4096 blocks) ----------------
__global__ void k_embed_hist(const int* __restrict__ ent_ids, const int* __restrict__ arw_pos,
                             const float* __restrict__ ent_tab, const float* __restrict__ pos_tab,
                             __bf16* __restrict__ hb, const int* __restrict__ dst,
                             int* __restrict__ deg) {
  int bid = blockIdx.x, tid = threadIdx.x;
  if (bid < 1563) {
    int t = bid * 256 + tid;            // over N*8 (1563*256 = 400128 >= 400000)
    if (t < NNODES * 8) {
      int n = t >> 3, c = t & 7;
      int e = ent_ids[n], a2 = arw_pos[n];
      #pragma unroll
      for (int i = 0; i < 4; ++i) {
        float4 a0 = ((const float4*)ent_tab)[e * 32 + c * 4 + i];
        float4 b0 = ((const float4*)pos_tab)[a2 * 32 + c * 4 + i];
        ushort4 o;
        o.x = f2b(a0.x + b0.x); o.y = f2b(a0.y + b0.y);
        o.z = f2b(a0.z + b0.z); o.w = f2b(a0.w + b0.w);
        ((ushort4*)hb)[n * 32 + c * 4 + i] = o;
      }
    }
  } else {
    int hbid = bid - 1563;              // 0..4095
    int part = hbid & 7;
    int lo = part * 6250, hi2 = lo + 6250;
    for (int e = (hbid >> 3) * 256 + tid; e < NEDGES; e += 512 * 256) {
      int d = dst[e];
      if (d >= lo && d < hi2) atomicAdd(&deg[d], 1);
    }
  }
}

// ---------------- prepA: blocks 0..48 chunk sums; 49..52 relsc; 53..340 transpose ----------------
__global__ void k_prepA(const int* __restrict__ deg, int* __restrict__ csum,
                        const float* __restrict__ Wr, const float* __restrict__ ar,
                        const float* __restrict__ rel_tab, float* __restrict__ relsc,
                        const float* __restrict__ Wh0, const float* __restrict__ Wh1,
                        const float* __restrict__ w10, const float* __restrict__ w11,
                        const float* __restrict__ w20, const float* __restrict__ w21,
                        __bf16* __restrict__ T0, __bf16* __restrict__ T1,
                        __bf16* __restrict__ T2, __bf16* __restrict__ T3,
                        __bf16* __restrict__ T4, __bf16* __restrict__ T5) {
  int bid = blockIdx.x, tid = threadIdx.x;
  if (bid < 49) {
    __shared__ int ws[16];
    int lane = tid & 63, w = tid >> 6;
    int i = bid * 1024 + tid;
    int v = (i < NNODES) ? deg[i] : 0;
    #pragma unroll
    for (int o = 1; o < 64; o <<= 1) v += __shfl_xor(v, o);
    if (lane == 0) ws[w] = v;
    __syncthreads();
    if (tid == 0) {
      int s = 0;
      #pragma unroll
      for (int k = 0; k < 16; ++k) s += ws[k];
      csum[bid] = s;
    }
  } else if (bid <= 52) {
    __shared__ float vr[1024];
    int d = tid >> 3, hh = tid & 7;
    float s = 0.f;
    #pragma unroll
    for (int k = 0; k < 16; ++k) s += Wr[d * 128 + hh * 16 + k] * ar[hh * 16 + k];
    vr[tid] = s;
    __syncthreads();
    int t = (bid - 49) * 1024 + tid;
    if (t < 500 * 8) {
      int r = t >> 3, h2 = t & 7;
      float acc = 0.f;
      for (int dd = 0; dd < 128; ++dd) acc += rel_tab[r * 128 + dd] * vr[dd * 8 + h2];
      relsc[t] = acc;
    }
  } else {
    // transpose+convert, coalesced WRITES
    int wb = bid - 53;
    const float* W; __bf16* T; int lr2, lc2;
    int sub;
    if (wb < 16)        { W = Wh0; T = T0; lr2 = 7; lc2 = 7; sub = wb; }
    else if (wb < 32)   { W = Wh1; T = T1; lr2 = 7; lc2 = 7; sub = wb - 16; }
    else if (wb < 96)   { W = w10; T = T2; lr2 = 7; lc2 = 9; sub = wb - 32; }
    else if (wb < 160)  { W = w11; T = T3; lr2 = 7; lc2 = 9; sub = wb - 96; }
    else if (wb < 224)  { W = w20; T = T4; lr2 = 9; lc2 = 7; sub = wb - 160; }
    else                { W = w21; T = T5; lr2 = 9; lc2 = 7; sub = wb - 224; }
    int idx = sub * 1024 + tid;
    int r = idx & ((1 << lr2) - 1);
    int c = idx >> lr2;
    T[((long)c << lr2) + r] = (__bf16)W[((long)r << lc2) + c];
  }
}

// ---------------- prepC: per-chunk local scan + inline csum scan (49 blocks x 1024) ----------------
__global__ void k_prepC(const int* __restrict__ deg, const int* __restrict__ csum,
                        int* __restrict__ rowptr, int* __restrict__ cursor) {
  __shared__ int wsum[16];
  __shared__ int s_coff, s_tot;
  int tid = threadIdx.x, lane = tid & 63, w = tid >> 6;
  if (tid < 64) {
    int v = (tid < 49) ? csum[tid] : 0;
    int x = v;
    #pragma unroll
    for (int o = 1; o < 64; o <<= 1) {
      int t = __shfl_up(x, o);
      if (tid >= o) x += t;
    }
    if (tid == (int)blockIdx.x) s_coff = x - v;
    if (tid == 48) s_tot = x;
  }
  int i = blockIdx.x * 1024 + tid;
  int v = (i < NNODES) ? deg[i] : 0;
  int x = v;
  #pragma unroll
  for (int o = 1; o < 64; o <<= 1) {
    int t = __shfl_up(x, o);
    if (lane >= o) x += t;
  }
  if (lane == 63) wsum[w] = x;
  __syncthreads();
  if (w == 0 && lane < 16) {
    int t = wsum[lane];
    #pragma unroll
    for (int o = 1; o < 16; o <<= 1) {
      int u = __shfl_up(t, o);
      if (lane >= o) t += u;
    }
    wsum[lane] = t;
  }
  __syncthreads();
  int add = s_coff + (w > 0 ? wsum[w - 1] : 0);
  if (i < NNODES) { rowptr[i] = add + x - v; cursor[i] = add + x - v; }
  if (blockIdx.x == 0 && tid == 0) rowptr[NNODES] = s_tot;
}

// ---------------- partitioned scatter: pack (src<<6)|(rel<<22) into CSR slots ----------------
__global__ __launch_bounds__(256) void k_scatter(
    const int* __restrict__ dst, const int* __restrict__ src,
    const int* __restrict__ rel_ids, int* __restrict__ cursor,
    uint32* __restrict__ packed) {
  int part = blockIdx.x & 7;
  int lo = part * 6250, hi2 = lo + 6250;
  int tid = threadIdx.x;
  for (int e = (int)(blockIdx.x >> 3) * 256 + tid; e < NEDGES; e += 256 * 256) {
    int d = dst[e];
    if (d >= lo && d < hi2) {
      int p = atomicAdd(&cursor[d], 1);
      packed[p] = ((uint32)src[e] << 6) | ((uint32)rel_ids[e] << 22);
    }
  }
}

// ---------------- fused: f = hb@Wht (MFMA) + attention-scores epilogue ----------------
__global__ __launch_bounds__(256) void k_gemm0s(
    const __bf16* __restrict__ A, const __bf16* __restrict__ Bt,
    __bf16* __restrict__ fout, const float* __restrict__ ah, const float* __restrict__ at,
    float* __restrict__ ssrc, float* __restrict__ sdst) {
  __shared__ char sA[16384];   // 128 rows x 64 bf16, XOR-swizzled
  __shared__ char sB[16384];
  const int tid = threadIdx.x;
  const int lane = tid & 63, wid = tid >> 6;
  const int wr = wid >> 1, wc = wid & 1;
  const int lr = lane & 15, hi = lane >> 4;
  const long row0 = (long)blockIdx.x * 128;
  f32x4 acc[4][4] = {};

  for (int kc = 0; kc < 2; ++kc) {
    __syncthreads();
    #pragma unroll
    for (int i = 0; i < 4; ++i) {
      int q = i * 256 + tid;
      int r = q >> 3, slot = q & 7;
      int sw = ((slot ^ (r & 7)) << 4);
      int4 av = *(const int4*)(A + (row0 + r) * 128 + kc * 64 + slot * 8);
      *(int4*)(sA + r * 128 + sw) = av;
      int4 bv = *(const int4*)(Bt + (long)r * 128 + kc * 64 + slot * 8);
      *(int4*)(sB + r * 128 + sw) = bv;
    }
    __syncthreads();
    #pragma unroll
    for (int ks = 0; ks < 2; ++ks) {
      bf16x8 af[4], bfr[4];
      #pragma unroll
      for (int m = 0; m < 4; ++m) {
        int r = wr * 64 + m * 16 + lr;
        int cb = ((ks * 4 + hi) ^ (r & 7)) << 4;
        af[m] = *(const bf16x8*)(sA + r * 128 + cb);
      }
      #pragma unroll
      for (int n = 0; n < 4; ++n) {
        int r = wc * 64 + n * 16 + lr;
        int cb = ((ks * 4 + hi) ^ (r & 7)) << 4;
        bfr[n] = *(const bf16x8*)(sB + r * 128 + cb);
      }
      #pragma unroll
      for (int m = 0; m < 4; ++m)
        #pragma unroll
        for (int n = 0; n < 4; ++n)
          acc[m][n] = __builtin_amdgcn_mfma_f32_16x16x32_bf16(af[m], bfr[n], acc[m][n], 0, 0, 0);
    }
  }

  float ahr[4], atr[4];
  #pragma unroll
  for (int n = 0; n < 4; ++n) {
    ahr[n] = ah[(wc * 4 + n) * 16 + lr];
    atr[n] = at[(wc * 4 + n) * 16 + lr];
  }
  #pragma unroll
  for (int m = 0; m < 4; ++m) {
    #pragma unroll
    for (int j = 0; j < 4; ++j) {
      long r = row0 + wr * 64 + m * 16 + hi * 4 + j;
      #pragma unroll
      for (int n = 0; n < 4; ++n) {
        long c = wc * 64 + n * 16 + lr;
        float v = acc[m][n][j];
        fout[r * 128 + c] = (__bf16)v;
        float ps = v * ahr[n], pt = v * atr[n];
        #pragma unroll
        for (int o = 1; o < 16; o <<= 1) { ps += __shfl_xor(ps, o); pt += __shfl_xor(pt, o); }
        if (lr == 0) {
          ssrc[r * 8 + wc * 4 + n] = ps;
          sdst[r * 8 + wc * 4 + n] = pt;
        }
      }
    }
  }
}

// ---------------- FFN gemm1: T = relu(ob @ w1t + c1) ----------------
template<int KDIM, int NB>
__global__ __launch_bounds__(256) void k_gemm(
    const __bf16* __restrict__ A, const __bf16* __restrict__ Bt,
    const float* __restrict__ bias, __bf16* __restrict__ outb) {
  __shared__ char sA[16384];
  __shared__ char sB[16384];
  const int tid = threadIdx.x;
  const int lane = tid & 63, wid = tid >> 6;
  const int wr = wid >> 1, wc = wid & 1;
  const int lr = lane & 15, hi = lane >> 4;
  const long row0 = (long)blockIdx.x * 128;
  const long col0 = (long)blockIdx.y * 128;
  f32x4 acc[4][4] = {};

  for (int kc = 0; kc < KDIM / 64; ++kc) {
    __syncthreads();
    #pragma unroll
    for (int i = 0; i < 4; ++i) {
      int q = i * 256 + tid;
      int r = q >> 3, slot = q & 7;
      int sw = ((slot ^ (r & 7)) << 4);
      int4 av = *(const int4*)(A + (row0 + r) * KDIM + kc * 64 + slot * 8);
      *(int4*)(sA + r * 128 + sw) = av;
      int4 bv = *(const int4*)(Bt + (col0 + r) * KDIM + kc * 64 + slot * 8);
      *(int4*)(sB + r * 128 + sw) = bv;
    }
    __syncthreads();
    #pragma unroll
    for (int ks = 0; ks < 2; ++ks) {
      bf16x8 af[4], bfr[4];
      #pragma unroll
      for (int m = 0; m < 4; ++m) {
        int r = wr * 64 + m * 16 + lr;
        int cb = ((ks * 4 + hi) ^ (r & 7)) << 4;
        af[m] = *(const bf16x8*)(sA + r * 128 + cb);
      }
      #pragma unroll
      for (int n = 0; n < 4; ++n) {
        int r = wc * 64 + n * 16 + lr;
        int cb = ((ks * 4 + hi) ^ (r & 7)) << 4;
        bfr[n] = *(const bf16x8*)(sB + r * 128 + cb);
      }
      #pragma unroll
      for (int m = 0; m < 4; ++m)
        #pragma unroll
        for (int n = 0; n < 4; ++n)
          acc[m][n] = __builtin_amdgcn_mfma_f32_16x16x32_bf16(af[m], bfr[n], acc[m][n], 0, 0, 0);
    }
  }

  #pragma unroll
  for (int m = 0; m < 4; ++m) {
    #pragma unroll
    for (int j = 0; j < 4; ++j) {
      long r = row0 + wr * 64 + m * 16 + hi * 4 + j;
      #pragma unroll
      for (int n = 0; n < 4; ++n) {
        long c = col0 + wc * 64 + n * 16 + lr;
        outb[r * NB + c] = (__bf16)fmaxf(acc[m][n][j] + bias[c], 0.f);
      }
    }
  }
}

// ---------------- FFN gemm2 + residual + LayerNorm fused (full rows per block) ----------------
__global__ __launch_bounds__(256) void k_gemm2ln(
    const __bf16* __restrict__ A, const __bf16* __restrict__ Bt,
    const float* __restrict__ bias, const __bf16* __restrict__ resid,
    const float* __restrict__ g, const float* __restrict__ b,
    __bf16* __restrict__ outb, float* __restrict__ outf) {
  __shared__ char smem[65536];         // sA(16K)+sB(16K) during K-loop; fp32 V[128][128] after
  char* sA = smem;
  char* sB = smem + 16384;
  float* sV = (float*)smem;
  const int tid = threadIdx.x;
  const int lane = tid & 63, wid = tid >> 6;
  const int wr = wid >> 1, wc = wid & 1;
  const int lr = lane & 15, hi = lane >> 4;
  const long row0 = (long)blockIdx.x * 128;
  f32x4 acc[4][4] = {};

  for (int kc = 0; kc < 8; ++kc) {     // K = 512
    __syncthreads();
    #pragma unroll
    for (int i = 0; i < 4; ++i) {
      int q = i * 256 + tid;
      int r = q >> 3, slot = q & 7;
      int sw = ((slot ^ (r & 7)) << 4);
      int4 av = *(const int4*)(A + (row0 + r) * 512 + kc * 64 + slot * 8);
      *(int4*)(sA + r * 128 + sw) = av;
      int4 bv = *(const int4*)(Bt + (long)r * 512 + kc * 64 + slot * 8);
      *(int4*)(sB + r * 128 + sw) = bv;
    }
    __syncthreads();
    #pragma unroll
    for (int ks = 0; ks < 2; ++ks) {
      bf16x8 af[4], bfr[4];
      #pragma unroll
      for (int m = 0; m < 4; ++m) {
        int r = wr * 64 + m * 16 + lr;
        int cb = ((ks * 4 + hi) ^ (r & 7)) << 4;
        af[m] = *(const bf16x8*)(sA + r * 128 + cb);
      }
      #pragma unroll
      for (int n = 0; n < 4; ++n) {
        int r = wc * 64 + n * 16 + lr;
        int cb = ((ks * 4 + hi) ^ (r & 7)) << 4;
        bfr[n] = *(const bf16x8*)(sB + r * 128 + cb);
      }
      #pragma unroll
      for (int m = 0; m < 4; ++m)
        #pragma unroll
        for (int n = 0; n < 4; ++n)
          acc[m][n] = __builtin_amdgcn_mfma_f32_16x16x32_bf16(af[m], bfr[n], acc[m][n], 0, 0, 0);
    }
  }
  __syncthreads();                     // tiles dead; smem becomes V scratch

  float biasr[4];
  #pragma unroll
  for (int n = 0; n < 4; ++n) biasr[n] = bias[wc * 64 + n * 16 + lr];
  #pragma unroll
  for (int m = 0; m < 4; ++m) {
    #pragma unroll
    for (int j = 0; j < 4; ++j) {
      int rloc = wr * 64 + m * 16 + hi * 4 + j;
      long r = row0 + rloc;
      #pragma unroll
      for (int n = 0; n < 4; ++n) {
        int c = wc * 64 + n * 16 + lr;
        sV[rloc * 128 + c] = acc[m][n][j] + biasr[n] + (float)resid[r * 128 + c];
      }
    }
  }
  __syncthreads();

  float2 gg = ((const float2*)g)[lane];
  float2 bb = ((const float2*)b)[lane];
  for (int rr = 0; rr < 32; ++rr) {
    int rloc = wid * 32 + rr;
    long r = row0 + rloc;
    float2 v = ((float2*)sV)[rloc * 64 + lane];
    float x = v.x, y = v.y;
    float s = x + y;
    #pragma unroll
    for (int o = 1; o < 64; o <<= 1) s += __shfl_xor(s, o);
    float mean = s * (1.f / 128.f);
    float dx = x - mean, dy = y - mean;
    float q = dx * dx + dy * dy;
    #pragma unroll
    for (int o = 1; o < 64; o <<= 1) q += __shfl_xor(q, o);
    float rs = rsqrtf(q * (1.f / 128.f) + 1e-5f);
    float ox = dx * rs * gg.x + bb.x;
    float oy = dy * rs * gg.y + bb.y;
    if (outf) ((float2*)outf)[r * 64 + lane] = make_float2(ox, oy);
    ((uint32*)outb)[r * 64 + lane] = ((uint32)f2b(oy) << 16) | (uint32)f2b(ox);
  }
}

// ---------------- edge softmax: register path (deg<=64), fallback 2-pass; fp16 att ----------------
__global__ void k_softmax(const int* __restrict__ rowptr, const uint32* __restrict__ packed,
                          const float* __restrict__ ssrc, const float* __restrict__ sdst,
                          const float* __restrict__ relsc, unsigned short* __restrict__ att16) {
  int lane = threadIdx.x & 63, wid = threadIdx.x >> 6;
  int n = blockIdx.x * 4 + wid;
  if (n >= NNODES) return;
  int start = rowptr[n], end = rowptr[n + 1];
  if (start == end) return;
  int hh = lane & 7, jj = lane >> 3;
  float sd = sdst[n * 8 + hh];
  float m = -1e30f, den = 0.f;
  int deg = end - start;

  if (deg <= 64) {
    uint32 pk[8];
    float ev[8];
    int end1 = end - 1;
    #pragma unroll
    for (int t = 0; t < 8; ++t)
      pk[t] = packed[min(start + t * 8 + jj, end1)];
    #pragma unroll
    for (int t = 0; t < 8; ++t)
      ev[t] = ssrc[((pk[t] & 0x3fffffu) >> 3) | (uint32)hh];    // src*8 + hh
    #pragma unroll
    for (int t = 0; t < 8; ++t) {
      int j = start + t * 8 + jj;
      float e = ev[t] + sd;
      if (relsc) e += relsc[((pk[t] >> 22) << 3) | (uint32)hh];
      e = (e >= 0.f) ? e : 0.2f * e;
      ev[t] = e;
      if (j < end) {
        float M = fmaxf(m, e);
        den = den * __expf(m - M) + __expf(e - M);
        m = M;
      }
    }
    #pragma unroll
    for (int o = 8; o < 64; o <<= 1) {
      float m2 = __shfl_xor(m, o), d2 = __shfl_xor(den, o);
      float M = fmaxf(m, m2);
      den = den * __expf(m - M) + d2 * __expf(m2 - M);
      m = M;
    }
    float inv = 1.f / (den + 1e-16f);
    #pragma unroll
    for (int t = 0; t < 8; ++t) {
      int j = start + t * 8 + jj;
      if (j < end) att16[j * 8 + hh] = f2h(__expf(ev[t] - m) * inv);
    }
  } else {
    for (int j0 = start; j0 < end; j0 += 8) {
      int j = j0 + jj;
      if (j < end) {
        uint32 p2 = packed[j];
        float e = ssrc[((p2 & 0x3fffffu) >> 3) | (uint32)hh] + sd;
        if (relsc) e += relsc[((p2 >> 22) << 3) | (uint32)hh];
        e = (e >= 0.f) ? e : 0.2f * e;
        att16[j * 8 + hh] = f2h(e);
        float M = fmaxf(m, e);
        den = den * __expf(m - M) + __expf(e - M);
        m = M;
      }
    }
    #pragma unroll
    for (int o = 8; o < 64; o <<= 1) {
      float m2 = __shfl_xor(m, o), d2 = __shfl_xor(den, o);
      float M = fmaxf(m, m2);
      den = den * __expf(m - M) + d2 * __expf(m2 - M);
      m = M;
    }
    float inv = 1.f / (den + 1e-16f);
    for (int j0 = start; j0 < end; j0 += 8) {
      int j = j0 + jj;
      if (j < end) att16[j * 8 + hh] = f2h(__expf(h2f(att16[j * 8 + hh]) - m) * inv);
    }
  }
}

// ---------------- diffusion hop: 16x4B gathers in flight, fp16 att direct loads ----------------
template<int FINAL>
__global__ __launch_bounds__(256) void k_hop(
    const int* __restrict__ rowptr, const uint32* __restrict__ packed,
    const unsigned short* __restrict__ att16, const __bf16* __restrict__ fin,
    const __bf16* __restrict__ f0, __bf16* __restrict__ fout,
    const __bf16* __restrict__ resid, const float* __restrict__ g,
    const float* __restrict__ b) {
  int lane = threadIdx.x & 63, wid = threadIdx.x >> 6;
  int n = blockIdx.x * 4 + wid;
  if (n >= NNODES) return;
  uint32 z = ((const uint32*)f0)[n * 64 + lane];
  uint32 rz = 0u;
  if (FINAL) rz = ((const uint32*)resid)[n * 64 + lane];
  int start = rowptr[n], end = rowptr[n + 1];
  int hsel = lane >> 3;
  float ax = 0.f, ay = 0.f;
  const uint32* fin2 = (const uint32*)fin;
  int deg = end - start;
  int nfull = deg >> 4;
  int j0 = start;
  for (int bb2 = 0; bb2 < nfull; ++bb2, j0 += 16) {   // full 16-edge batches, unmasked
    #pragma unroll
    for (int k = 0; k < 16; ++k) {
      float a = h2f(att16[(j0 + k) * 8 + hsel]);
      uint32 pk = packed[j0 + k];
      uint32 v = fin2[(pk & 0x3fffffu) | (uint32)lane];
      ax += a * b2f(v & 0xffffu);
      ay += a * b2fh(v);
    }
  }
  int nb = deg & 15;
  if (nb) {                                           // masked tail: 8 + optional 8
    int end1 = end - 1;
    #pragma unroll
    for (int k = 0; k < 8; ++k) {
      int jc = min(j0 + k, end1);
      float a = h2f(att16[jc * 8 + hsel]);
      a = (k < nb) ? a : 0.f;
      uint32 pk = packed[jc];
      uint32 v = fin2[(pk & 0x3fffffu) | (uint32)lane];
      ax += a * b2f(v & 0xffffu);
      ay += a * b2fh(v);
    }
    if (nb > 8) {
      #pragma unroll
      for (int k = 8; k < 16; ++k) {
        int jc = min(j0 + k, end1);
        float a = h2f(att16[jc * 8 + hsel]);
        a = (k < nb) ? a : 0.f;
        uint32 pk = packed[jc];
        uint32 v = fin2[(pk & 0x3fffffu) | (uint32)lane];
        ax += a * b2f(v & 0xffffu);
        ay += a * b2fh(v);
      }
    }
  }
  float ox = 0.15f * b2f(z & 0xffffu) + 0.85f * ax;
  float oy = 0.15f * b2fh(z) + 0.85f * ay;
  if (!FINAL) {
    ((uint32*)fout)[n * 64 + lane] = ((uint32)f2b(oy) << 16) | (uint32)f2b(ox);
  } else {
    float x = ox + b2f(rz & 0xffffu);
    float y = oy + b2fh(rz);
    float s = x + y;
    #pragma unroll
    for (int o = 1; o < 64; o <<= 1) s += __shfl_xor(s, o);
    float mean = s * (1.f / 128.f);
    float dx = x - mean, dy = y - mean;
    float q = dx * dx + dy * dy;
    #pragma unroll
    for (int o = 1; o < 64; o <<= 1) q += __shfl_xor(q, o);
    float rs2 = rsqrtf(q * (1.f / 128.f) + 1e-5f);
    float2 gg = ((const float2*)g)[lane];
    float2 bb = ((const float2*)b)[lane];
    float o1 = dx * rs2 * gg.x + bb.x;
    float o2 = dy * rs2 * gg.y + bb.y;
    ((uint32*)fout)[n * 64 + lane] = ((uint32)f2b(o2) << 16) | (uint32)f2b(o1);
  }
}

// ---------------- final gather (fp32) ----------------
__global__ void k_gather(const int* __restrict__ ids, const float* __restrict__ h,
                         float* __restrict__ out) {
  int t = blockIdx.x * 256 + threadIdx.x;   // 512*32
  if (t >= 512 * 32) return;
  int b = t >> 5, c = t & 31;
  ((float4*)out)[t] = ((const float4*)h)[(long)ids[b] * 32 + c];
}

// ---------------- host side ----------------
struct LayerW {
  const float *Wh, *ah, *at, *g1, *b1, *w1, *c1, *w2, *c2, *g2, *b2;
};

extern "C" void kernel_launch(void* const* d_in, const int* in_sizes, int n_in,
                              void* d_out, int out_size, void* d_ws, size_t ws_size,
                              hipStream_t stream) {
  const int* ent_ids   = (const int*)d_in[0];
  const int* rel_ids   = (const int*)d_in[1];
  const int* arw_pos   = (const int*)d_in[2];
  const int* src       = (const int*)d_in[3];
  const int* dst       = (const int*)d_in[4];
  const int* batch_ids = (const int*)d_in[5];
  const float* ent_tab = (const float*)d_in[6];
  const float* rel_tab = (const float*)d_in[7];
  const float* pos_tab = (const float*)d_in[8];

  LayerW L0 = {(const float*)d_in[9],  (const float*)d_in[11], (const float*)d_in[12],
               (const float*)d_in[14], (const float*)d_in[15], (const float*)d_in[16],
               (const float*)d_in[17], (const float*)d_in[18], (const float*)d_in[19],
               (const float*)d_in[20], (const float*)d_in[21]};
  const float* l0_Wr = (const float*)d_in[10];
  const float* l0_ar = (const float*)d_in[13];
  LayerW L1 = {(const float*)d_in[22], (const float*)d_in[23], (const float*)d_in[24],
               (const float*)d_in[25], (const float*)d_in[26], (const float*)d_in[27],
               (const float*)d_in[28], (const float*)d_in[29], (const float*)d_in[30],
               (const float*)d_in[31], (const float*)d_in[32]};

  // ---- workspace carve ----
  char* p = (char*)d_ws;
  auto alloc = [&](size_t bytes) { char* q = p; p += (bytes + 255) & ~(size_t)255; return q; };
  __bf16* hb = (__bf16*)alloc((size_t)NP * 128 * 2);
  __bf16* f  = (__bf16*)alloc((size_t)NP * 128 * 2);
  __bf16* fb = (__bf16*)alloc((size_t)NP * 128 * 2);   // must follow f (y aliases f+fb)
  __bf16* fa = (__bf16*)alloc((size_t)NP * 128 * 2);
  __bf16* ob = (__bf16*)alloc((size_t)NP * 128 * 2);
  char*   U  = alloc((size_t)NP * 512 * 2);            // union: att16 (E*8 fp16) | T (bf16 NP*512)
  unsigned short* att16 = (unsigned short*)U;
  __bf16* T   = (__bf16*)U;
  float*  y   = (float*)f;                             // fp32 NP*128, spans f+fb
  float* ssrc  = (float*)alloc((size_t)NP * 8 * 4);
  float* sdst  = (float*)alloc((size_t)NP * 8 * 4);
  float* relsc = (float*)alloc(500 * 8 * 4);
  __bf16* Wht0 = (__bf16*)alloc(128 * 128 * 2);
  __bf16* Wht1 = (__bf16*)alloc(128 * 128 * 2);
  __bf16* w1t0 = (__bf16*)alloc(512 * 128 * 2);
  __bf16* w1t1 = (__bf16*)alloc(512 * 128 * 2);
  __bf16* w2t0 = (__bf16*)alloc(128 * 512 * 2);
  __bf16* w2t1 = (__bf16*)alloc(128 * 512 * 2);
  int* deg    = (int*)alloc(NNODES * 4);
  int* rowptr = (int*)alloc((NNODES + 1) * 4);
  int* cursor = (int*)alloc(NNODES * 4);
  int* csum   = (int*)alloc(64 * 4);
  uint32* packed = (uint32*)alloc((size_t)NEDGES * 4);

  // zero pads of GEMM A-inputs + degree array
  hipMemsetAsync(hb + (size_t)NNODES * 128, 0, (size_t)(NP - NNODES) * 128 * 2, stream);
  hipMemsetAsync(ob + (size_t)NNODES * 128, 0, (size_t)(NP - NNODES) * 128 * 2, stream);
  hipMemsetAsync(deg, 0, NNODES * sizeof(int), stream);

  k_embed_hist<<<1563 + 4096, 256, 0, stream>>>(ent_ids, arw_pos, ent_tab, pos_tab, hb, dst, deg);
  k_prepA<<<341, 1024, 0, stream>>>(deg, csum, l0_Wr, l0_ar, rel_tab, relsc,
                                    L0.Wh, L1.Wh, L0.w1, L1.w1, L0.w2, L1.w2,
                                    Wht0, Wht1, w1t0, w1t1, w2t0, w2t1);
  k_prepC<<<49, 1024, 0, stream>>>(deg, csum, rowptr, cursor);
  k_scatter<<<2048, 256, 0, stream>>>(dst, src, rel_ids, cursor, packed);

  const int NB4 = (NNODES + 3) / 4;
  for (int L = 0; L < 2; ++L) {
    const LayerW& W = L ? L1 : L0;
    const __bf16* Wht = L ? Wht1 : Wht0;
    const __bf16* w1t = L ? w1t1 : w1t0;
    const __bf16* w2t = L ? w2t1 : w2t0;
    const float* rsc  = L ? nullptr : relsc;

    k_gemm0s<<<391, 256, 0, stream>>>(hb, Wht, f, W.ah, W.at, ssrc, sdst);
    k_softmax<<<NB4, 256, 0, stream>>>(rowptr, packed, ssrc, sdst, rsc, att16);
    k_hop<0><<<NB4, 256, 0, stream>>>(rowptr, packed, att16, f, f, fa, nullptr, nullptr, nullptr);
    k_hop<0><<<NB4, 256, 0, stream>>>(rowptr, packed, att16, fa, f, fb, nullptr, nullptr, nullptr);
    k_hop<1><<<NB4, 256, 0, stream>>>(rowptr, packed, att16, fb, f, ob, hb, W.g1, W.b1);
    k_gemm<128, 512><<<dim3(391, 4), 256, 0, stream>>>(ob, w1t, W.c1, T);
    k_gemm2ln<<<391, 256, 0, stream>>>(T, w2t, W.c2, ob, W.g2, W.b2, hb,
                                       (L == 1) ? y : nullptr);
  }

  k_gather<<<64, 256, 0, stream>>>(batch_ids, y, (float*)d_out);
}

// Round 14
// 494.078 us; speedup vs baseline: 1.0652x; 1.0066x over previous
//
#include <hip/hip_runtime.h>
#include <hip/hip_bf16.h>

#define NNODES 50000
#define NEDGES 800000
#define NP 50048            // 391 * 128, padded node count
#define DIM 128
#define HEADS 8
#define FFNDIM 512

typedef __bf16 bf16x8 __attribute__((ext_vector_type(8)));
typedef float f32x4 __attribute__((ext_vector_type(4)));
typedef unsigned int uint32;
typedef unsigned short ushort16;

__device__ __forceinline__ float b2f(uint32 u) {
  union { uint32 i; float f; } x; x.i = u << 16; return x.f;
}
__device__ __forceinline__ float b2fh(uint32 u) {   // high half, no shift needed
  union { uint32 i; float f; } x; x.i = u & 0xffff0000u; return x.f;
}
__device__ __forceinline__ ushort16 f2b(float f) {
  __bf16 h = (__bf16)f; return __builtin_bit_cast(ushort16, h);
}
__device__ __forceinline__ float h2f(unsigned short u) {
  return (float)__builtin_bit_cast(_Float16, u);
}
__device__ __forceinline__ unsigned short f2h(float f) {
  return __builtin_bit_cast(unsigned short, (_Float16)f);
}

// ---- mega prep/embed kernel block layout ----
#define EMB_B   1563          // embed: 8 threads/node
#define HIST_B  4096          // partitioned degree histogram
#define TR_B    1152          // weight transpose: 6 matrices
#define REL_B   16            // relsc table
// grid = EMB_B + HIST_B + TR_B + REL_B = 6827

__global__ void k_embed_hist(const int* __restrict__ ent_ids, const int* __restrict__ arw_pos,
                             const float* __restrict__ ent_tab, const float* __restrict__ pos_tab,
                             __bf16* __restrict__ hb, const int* __restrict__ dst,
                             int* __restrict__ deg,
                             const float* __restrict__ Wr, const float* __restrict__ ar,
                             const float* __restrict__ rel_tab, float* __restrict__ relsc,
                             const float* __restrict__ Wh0, const float* __restrict__ Wh1,
                             const float* __restrict__ w10, const float* __restrict__ w11,
                             const float* __restrict__ w20, const float* __restrict__ w21,
                             __bf16* __restrict__ T0, __bf16* __restrict__ T1,
                             __bf16* __restrict__ T2, __bf16* __restrict__ T3,
                             __bf16* __restrict__ T4, __bf16* __restrict__ T5) {
  int bid = blockIdx.x, tid = threadIdx.x;
  if (bid < EMB_B) {
    int t = bid * 256 + tid;            // over N*8 (1563*256 = 400128 >= 400000)
    if (t < NNODES * 8) {
      int n = t >> 3, c = t & 7;
      int e = ent_ids[n], a2 = arw_pos[n];
      #pragma unroll
      for (int i = 0; i < 4; ++i) {
        float4 a0 = ((const float4*)ent_tab)[e * 32 + c * 4 + i];
        float4 b0 = ((const float4*)pos_tab)[a2 * 32 + c * 4 + i];
        ushort4 o;
        o.x = f2b(a0.x + b0.x); o.y = f2b(a0.y + b0.y);
        o.z = f2b(a0.z + b0.z); o.w = f2b(a0.w + b0.w);
        ((ushort4*)hb)[n * 32 + c * 4 + i] = o;
      }
    }
  } else if (bid < EMB_B + HIST_B) {
    int hbid = bid - EMB_B;             // 0..4095
    int part = hbid & 7;
    int lo = part * 6250, hi2 = lo + 6250;
    for (int e = (hbid >> 3) * 256 + tid; e < NEDGES; e += 512 * 256) {
      int d = dst[e];
      if (d >= lo && d < hi2) atomicAdd(&deg[d], 1);
    }
  } else if (bid < EMB_B + HIST_B + TR_B) {
    // weight transpose+convert, coalesced writes
    int wb = bid - (EMB_B + HIST_B);
    const float* W; __bf16* T; int lr2, lc2;
    int sub;
    if (wb < 64)        { W = Wh0; T = T0; lr2 = 7; lc2 = 7; sub = wb; }
    else if (wb < 128)  { W = Wh1; T = T1; lr2 = 7; lc2 = 7; sub = wb - 64; }
    else if (wb < 384)  { W = w10; T = T2; lr2 = 7; lc2 = 9; sub = wb - 128; }
    else if (wb < 640)  { W = w11; T = T3; lr2 = 7; lc2 = 9; sub = wb - 384; }
    else if (wb < 896)  { W = w20; T = T4; lr2 = 9; lc2 = 7; sub = wb - 640; }
    else                { W = w21; T = T5; lr2 = 9; lc2 = 7; sub = wb - 896; }
    int idx = sub * 256 + tid;
    int r = idx & ((1 << lr2) - 1);
    int c = idx >> lr2;
    T[((long)c << lr2) + r] = (__bf16)W[((long)r << lc2) + c];
  } else {
    // relsc[r][h] = sum_d rel_tab[r][d] * (Wr@ar)[d][h]
    __shared__ float vr[1024];
    for (int i = tid; i < 1024; i += 256) {
      int d = i >> 3, hh = i & 7;
      float s = 0.f;
      #pragma unroll
      for (int k = 0; k < 16; ++k) s += Wr[d * 128 + hh * 16 + k] * ar[hh * 16 + k];
      vr[i] = s;
    }
    __syncthreads();
    int t = (bid - (EMB_B + HIST_B + TR_B)) * 256 + tid;
    if (t < 500 * 8) {
      int r = t >> 3, h2 = t & 7;
      float acc = 0.f;
      for (int dd = 0; dd < 128; ++dd) acc += rel_tab[r * 128 + dd] * vr[dd * 8 + h2];
      relsc[t] = acc;
    }
  }
}

// ---------------- prepA: 49 chunk sums of deg ----------------
__global__ void k_prepA(const int* __restrict__ deg, int* __restrict__ csum) {
  __shared__ int ws[16];
  int tid = threadIdx.x, lane = tid & 63, w = tid >> 6;
  int i = blockIdx.x * 1024 + tid;
  int v = (i < NNODES) ? deg[i] : 0;
  #pragma unroll
  for (int o = 1; o < 64; o <<= 1) v += __shfl_xor(v, o);
  if (lane == 0) ws[w] = v;
  __syncthreads();
  if (tid == 0) {
    int s = 0;
    #pragma unroll
    for (int k = 0; k < 16; ++k) s += ws[k];
    csum[blockIdx.x] = s;
  }
}

// ---------------- prepC: per-chunk local scan + inline csum scan (49 blocks x 1024) ----------------
__global__ void k_prepC(const int* __restrict__ deg, const int* __restrict__ csum,
                        int* __restrict__ rowptr, int* __restrict__ cursor) {
  __shared__ int wsum[16];
  __shared__ int s_coff, s_tot;
  int tid = threadIdx.x, lane = tid & 63, w = tid >> 6;
  if (tid < 64) {
    int v = (tid < 49) ? csum[tid] : 0;
    int x = v;
    #pragma unroll
    for (int o = 1; o < 64; o <<= 1) {
      int t = __shfl_up(x, o);
      if (tid >= o) x += t;
    }
    if (tid == (int)blockIdx.x) s_coff = x - v;
    if (tid == 48) s_tot = x;
  }
  int i = blockIdx.x * 1024 + tid;
  int v = (i < NNODES) ? deg[i] : 0;
  int x = v;
  #pragma unroll
  for (int o = 1; o < 64; o <<= 1) {
    int t = __shfl_up(x, o);
    if (lane >= o) x += t;
  }
  if (lane == 63) wsum[w] = x;
  __syncthreads();
  if (w == 0 && lane < 16) {
    int t = wsum[lane];
    #pragma unroll
    for (int o = 1; o < 16; o <<= 1) {
      int u = __shfl_up(t, o);
      if (lane >= o) t += u;
    }
    wsum[lane] = t;
  }
  __syncthreads();
  int add = s_coff + (w > 0 ? wsum[w - 1] : 0);
  if (i < NNODES) { rowptr[i] = add + x - v; cursor[i] = add + x - v; }
  if (blockIdx.x == 0 && tid == 0) rowptr[NNODES] = s_tot;
}

// ---------------- partitioned scatter: pack (src<<6)|(rel<<22) into CSR slots ----------------
__global__ __launch_bounds__(256) void k_scatter(
    const int* __restrict__ dst, const int* __restrict__ src,
    const int* __restrict__ rel_ids, int* __restrict__ cursor,
    uint32* __restrict__ packed) {
  int part = blockIdx.x & 7;
  int lo = part * 6250, hi2 = lo + 6250;
  int tid = threadIdx.x;
  for (int e = (int)(blockIdx.x >> 3) * 256 + tid; e < NEDGES; e += 256 * 256) {
    int d = dst[e];
    if (d >= lo && d < hi2) {
      int p = atomicAdd(&cursor[d], 1);
      packed[p] = ((uint32)src[e] << 6) | ((uint32)rel_ids[e] << 22);
    }
  }
}

// ---------------- fused: f = hb@Wht (MFMA) + attention-scores epilogue ----------------
__global__ __launch_bounds__(256) void k_gemm0s(
    const __bf16* __restrict__ A, const __bf16* __restrict__ Bt,
    __bf16* __restrict__ fout, const float* __restrict__ ah, const float* __restrict__ at,
    float* __restrict__ ssrc, float* __restrict__ sdst) {
  __shared__ char sA[16384];   // 128 rows x 64 bf16, XOR-swizzled
  __shared__ char sB[16384];
  const int tid = threadIdx.x;
  const int lane = tid & 63, wid = tid >> 6;
  const int wr = wid >> 1, wc = wid & 1;
  const int lr = lane & 15, hi = lane >> 4;
  const long row0 = (long)blockIdx.x * 128;
  f32x4 acc[4][4] = {};

  for (int kc = 0; kc < 2; ++kc) {
    __syncthreads();
    #pragma unroll
    for (int i = 0; i < 4; ++i) {
      int q = i * 256 + tid;
      int r = q >> 3, slot = q & 7;
      int sw = ((slot ^ (r & 7)) << 4);
      int4 av = *(const int4*)(A + (row0 + r) * 128 + kc * 64 + slot * 8);
      *(int4*)(sA + r * 128 + sw) = av;
      int4 bv = *(const int4*)(Bt + (long)r * 128 + kc * 64 + slot * 8);
      *(int4*)(sB + r * 128 + sw) = bv;
    }
    __syncthreads();
    #pragma unroll
    for (int ks = 0; ks < 2; ++ks) {
      bf16x8 af[4], bfr[4];
      #pragma unroll
      for (int m = 0; m < 4; ++m) {
        int r = wr * 64 + m * 16 + lr;
        int cb = ((ks * 4 + hi) ^ (r & 7)) << 4;
        af[m] = *(const bf16x8*)(sA + r * 128 + cb);
      }
      #pragma unroll
      for (int n = 0; n < 4; ++n) {
        int r = wc * 64 + n * 16 + lr;
        int cb = ((ks * 4 + hi) ^ (r & 7)) << 4;
        bfr[n] = *(const bf16x8*)(sB + r * 128 + cb);
      }
      #pragma unroll
      for (int m = 0; m < 4; ++m)
        #pragma unroll
        for (int n = 0; n < 4; ++n)
          acc[m][n] = __builtin_amdgcn_mfma_f32_16x16x32_bf16(af[m], bfr[n], acc[m][n], 0, 0, 0);
    }
  }

  float ahr[4], atr[4];
  #pragma unroll
  for (int n = 0; n < 4; ++n) {
    ahr[n] = ah[(wc * 4 + n) * 16 + lr];
    atr[n] = at[(wc * 4 + n) * 16 + lr];
  }
  #pragma unroll
  for (int m = 0; m < 4; ++m) {
    #pragma unroll
    for (int j = 0; j < 4; ++j) {
      long r = row0 + wr * 64 + m * 16 + hi * 4 + j;
      #pragma unroll
      for (int n = 0; n < 4; ++n) {
        long c = wc * 64 + n * 16 + lr;
        float v = acc[m][n][j];
        fout[r * 128 + c] = (__bf16)v;
        float ps = v * ahr[n], pt = v * atr[n];
        #pragma unroll
        for (int o = 1; o < 16; o <<= 1) { ps += __shfl_xor(ps, o); pt += __shfl_xor(pt, o); }
        if (lr == 0) {
          ssrc[r * 8 + wc * 4 + n] = ps;
          sdst[r * 8 + wc * 4 + n] = pt;
        }
      }
    }
  }
}

// ---------------- FFN gemm1: T = relu(ob @ w1t + c1) ----------------
template<int KDIM, int NB>
__global__ __launch_bounds__(256) void k_gemm(
    const __bf16* __restrict__ A, const __bf16* __restrict__ Bt,
    const float* __restrict__ bias, __bf16* __restrict__ outb) {
  __shared__ char sA[16384];
  __shared__ char sB[16384];
  const int tid = threadIdx.x;
  const int lane = tid & 63, wid = tid >> 6;
  const int wr = wid >> 1, wc = wid & 1;
  const int lr = lane & 15, hi = lane >> 4;
  const long row0 = (long)blockIdx.x * 128;
  const long col0 = (long)blockIdx.y * 128;
  f32x4 acc[4][4] = {};

  for (int kc = 0; kc < KDIM / 64; ++kc) {
    __syncthreads();
    #pragma unroll
    for (int i = 0; i < 4; ++i) {
      int q = i * 256 + tid;
      int r = q >> 3, slot = q & 7;
      int sw = ((slot ^ (r & 7)) << 4);
      int4 av = *(const int4*)(A + (row0 + r) * KDIM + kc * 64 + slot * 8);
      *(int4*)(sA + r * 128 + sw) = av;
      int4 bv = *(const int4*)(Bt + (col0 + r) * KDIM + kc * 64 + slot * 8);
      *(int4*)(sB + r * 128 + sw) = bv;
    }
    __syncthreads();
    #pragma unroll
    for (int ks = 0; ks < 2; ++ks) {
      bf16x8 af[4], bfr[4];
      #pragma unroll
      for (int m = 0; m < 4; ++m) {
        int r = wr * 64 + m * 16 + lr;
        int cb = ((ks * 4 + hi) ^ (r & 7)) << 4;
        af[m] = *(const bf16x8*)(sA + r * 128 + cb);
      }
      #pragma unroll
      for (int n = 0; n < 4; ++n) {
        int r = wc * 64 + n * 16 + lr;
        int cb = ((ks * 4 + hi) ^ (r & 7)) << 4;
        bfr[n] = *(const bf16x8*)(sB + r * 128 + cb);
      }
      #pragma unroll
      for (int m = 0; m < 4; ++m)
        #pragma unroll
        for (int n = 0; n < 4; ++n)
          acc[m][n] = __builtin_amdgcn_mfma_f32_16x16x32_bf16(af[m], bfr[n], acc[m][n], 0, 0, 0);
    }
  }

  #pragma unroll
  for (int m = 0; m < 4; ++m) {
    #pragma unroll
    for (int j = 0; j < 4; ++j) {
      long r = row0 + wr * 64 + m * 16 + hi * 4 + j;
      #pragma unroll
      for (int n = 0; n < 4; ++n) {
        long c = col0 + wc * 64 + n * 16 + lr;
        outb[r * NB + c] = (__bf16)fmaxf(acc[m][n][j] + bias[c], 0.f);
      }
    }
  }
}

// ---------------- FFN gemm2 + residual + LayerNorm fused (full rows per block) ----------------
__global__ __launch_bounds__(256) void k_gemm2ln(
    const __bf16* __restrict__ A, const __bf16* __restrict__ Bt,
    const float* __restrict__ bias, const __bf16* __restrict__ resid,
    const float* __restrict__ g, const float* __restrict__ b,
    __bf16* __restrict__ outb, float* __restrict__ outf) {
  __shared__ char smem[65536];         // sA(16K)+sB(16K) during K-loop; fp32 V[128][128] after
  char* sA = smem;
  char* sB = smem + 16384;
  float* sV = (float*)smem;
  const int tid = threadIdx.x;
  const int lane = tid & 63, wid = tid >> 6;
  const int wr = wid >> 1, wc = wid & 1;
  const int lr = lane & 15, hi = lane >> 4;
  const long row0 = (long)blockIdx.x * 128;
  f32x4 acc[4][4] = {};

  for (int kc = 0; kc < 8; ++kc) {     // K = 512
    __syncthreads();
    #pragma unroll
    for (int i = 0; i < 4; ++i) {
      int q = i * 256 + tid;
      int r = q >> 3, slot = q & 7;
      int sw = ((slot ^ (r & 7)) << 4);
      int4 av = *(const int4*)(A + (row0 + r) * 512 + kc * 64 + slot * 8);
      *(int4*)(sA + r * 128 + sw) = av;
      int4 bv = *(const int4*)(Bt + (long)r * 512 + kc * 64 + slot * 8);
      *(int4*)(sB + r * 128 + sw) = bv;
    }
    __syncthreads();
    #pragma unroll
    for (int ks = 0; ks < 2; ++ks) {
      bf16x8 af[4], bfr[4];
      #pragma unroll
      for (int m = 0; m < 4; ++m) {
        int r = wr * 64 + m * 16 + lr;
        int cb = ((ks * 4 + hi) ^ (r & 7)) << 4;
        af[m] = *(const bf16x8*)(sA + r * 128 + cb);
      }
      #pragma unroll
      for (int n = 0; n < 4; ++n) {
        int r = wc * 64 + n * 16 + lr;
        int cb = ((ks * 4 + hi) ^ (r & 7)) << 4;
        bfr[n] = *(const bf16x8*)(sB + r * 128 + cb);
      }
      #pragma unroll
      for (int m = 0; m < 4; ++m)
        #pragma unroll
        for (int n = 0; n < 4; ++n)
          acc[m][n] = __builtin_amdgcn_mfma_f32_16x16x32_bf16(af[m], bfr[n], acc[m][n], 0, 0, 0);
    }
  }
  __syncthreads();                     // tiles dead; smem becomes V scratch

  float biasr[4];
  #pragma unroll
  for (int n = 0; n < 4; ++n) biasr[n] = bias[wc * 64 + n * 16 + lr];
  #pragma unroll
  for (int m = 0; m < 4; ++m) {
    #pragma unroll
    for (int j = 0; j < 4; ++j) {
      int rloc = wr * 64 + m * 16 + hi * 4 + j;
      long r = row0 + rloc;
      #pragma unroll
      for (int n = 0; n < 4; ++n) {
        int c = wc * 64 + n * 16 + lr;
        sV[rloc * 128 + c] = acc[m][n][j] + biasr[n] + (float)resid[r * 128 + c];
      }
    }
  }
  __syncthreads();

  float2 gg = ((const float2*)g)[lane];
  float2 bb = ((const float2*)b)[lane];
  for (int rr = 0; rr < 32; ++rr) {
    int rloc = wid * 32 + rr;
    long r = row0 + rloc;
    float2 v = ((float2*)sV)[rloc * 64 + lane];
    float x = v.x, y = v.y;
    float s = x + y;
    #pragma unroll
    for (int o = 1; o < 64; o <<= 1) s += __shfl_xor(s, o);
    float mean = s * (1.f / 128.f);
    float dx = x - mean, dy = y - mean;
    float q = dx * dx + dy * dy;
    #pragma unroll
    for (int o = 1; o < 64; o <<= 1) q += __shfl_xor(q, o);
    float rs = rsqrtf(q * (1.f / 128.f) + 1e-5f);
    float ox = dx * rs * gg.x + bb.x;
    float oy = dy * rs * gg.y + bb.y;
    if (outf) ((float2*)outf)[r * 64 + lane] = make_float2(ox, oy);
    ((uint32*)outb)[r * 64 + lane] = ((uint32)f2b(oy) << 16) | (uint32)f2b(ox);
  }
}

// ---------------- edge softmax: register path (deg<=64), fallback 2-pass; fp16 att ----------------
__global__ void k_softmax(const int* __restrict__ rowptr, const uint32* __restrict__ packed,
                          const float* __restrict__ ssrc, const float* __restrict__ sdst,
                          const float* __restrict__ relsc, unsigned short* __restrict__ att16) {
  int lane = threadIdx.x & 63, wid = threadIdx.x >> 6;
  int n = blockIdx.x * 4 + wid;
  if (n >= NNODES) return;
  int start = rowptr[n], end = rowptr[n + 1];
  if (start == end) return;
  int hh = lane & 7, jj = lane >> 3;
  float sd = sdst[n * 8 + hh];
  float m = -1e30f, den = 0.f;
  int deg = end - start;

  if (deg <= 64) {
    uint32 pk[8];
    float ev[8];
    int end1 = end - 1;
    #pragma unroll
    for (int t = 0; t < 8; ++t)
      pk[t] = packed[min(start + t * 8 + jj, end1)];
    #pragma unroll
    for (int t = 0; t < 8; ++t)
      ev[t] = ssrc[((pk[t] & 0x3fffffu) >> 3) | (uint32)hh];    // src*8 + hh
    #pragma unroll
    for (int t = 0; t < 8; ++t) {
      int j = start + t * 8 + jj;
      float e = ev[t] + sd;
      if (relsc) e += relsc[((pk[t] >> 22) << 3) | (uint32)hh];
      e = (e >= 0.f) ? e : 0.2f * e;
      ev[t] = e;
      if (j < end) {
        float M = fmaxf(m, e);
        den = den * __expf(m - M) + __expf(e - M);
        m = M;
      }
    }
    #pragma unroll
    for (int o = 8; o < 64; o <<= 1) {
      float m2 = __shfl_xor(m, o), d2 = __shfl_xor(den, o);
      float M = fmaxf(m, m2);
      den = den * __expf(m - M) + d2 * __expf(m2 - M);
      m = M;
    }
    float inv = 1.f / (den + 1e-16f);
    #pragma unroll
    for (int t = 0; t < 8; ++t) {
      int j = start + t * 8 + jj;
      if (j < end) att16[j * 8 + hh] = f2h(__expf(ev[t] - m) * inv);
    }
  } else {
    for (int j0 = start; j0 < end; j0 += 8) {
      int j = j0 + jj;
      if (j < end) {
        uint32 p2 = packed[j];
        float e = ssrc[((p2 & 0x3fffffu) >> 3) | (uint32)hh] + sd;
        if (relsc) e += relsc[((p2 >> 22) << 3) | (uint32)hh];
        e = (e >= 0.f) ? e : 0.2f * e;
        att16[j * 8 + hh] = f2h(e);
        float M = fmaxf(m, e);
        den = den * __expf(m - M) + __expf(e - M);
        m = M;
      }
    }
    #pragma unroll
    for (int o = 8; o < 64; o <<= 1) {
      float m2 = __shfl_xor(m, o), d2 = __shfl_xor(den, o);
      float M = fmaxf(m, m2);
      den = den * __expf(m - M) + d2 * __expf(m2 - M);
      m = M;
    }
    float inv = 1.f / (den + 1e-16f);
    for (int j0 = start; j0 < end; j0 += 8) {
      int j = j0 + jj;
      if (j < end) att16[j * 8 + hh] = f2h(__expf(h2f(att16[j * 8 + hh]) - m) * inv);
    }
  }
}

// ---------------- diffusion hop: register-staged batches (32 loads then 16 gathers) ----------------
template<int FINAL>
__global__ __launch_bounds__(256) void k_hop(
    const int* __restrict__ rowptr, const uint32* __restrict__ packed,
    const unsigned short* __restrict__ att16, const __bf16* __restrict__ fin,
    const __bf16* __restrict__ f0, __bf16* __restrict__ fout,
    const __bf16* __restrict__ resid, const float* __restrict__ g,
    const float* __restrict__ b) {
  int lane = threadIdx.x & 63, wid = threadIdx.x >> 6;
  int n = blockIdx.x * 4 + wid;
  if (n >= NNODES) return;
  uint32 z = ((const uint32*)f0)[n * 64 + lane];
  uint32 rz = 0u;
  if (FINAL) rz = ((const uint32*)resid)[n * 64 + lane];
  int start = rowptr[n], end = rowptr[n + 1];
  int hsel = lane >> 3;
  float ax = 0.f, ay = 0.f;
  const uint32* fin2 = (const uint32*)fin;
  int deg = end - start;
  int nfull = deg >> 4;
  int j0 = start;
  for (int bb2 = 0; bb2 < nfull; ++bb2, j0 += 16) {   // full 16-edge batches, staged
    uint32 pks[16];
    unsigned short avs[16];
    #pragma unroll
    for (int k = 0; k < 16; ++k) pks[k] = packed[j0 + k];
    #pragma unroll
    for (int k = 0; k < 16; ++k) avs[k] = att16[(j0 + k) * 8 + hsel];
    #pragma unroll
    for (int k = 0; k < 16; ++k) {
      uint32 v = fin2[(pks[k] & 0x3fffffu) | (uint32)lane];
      float a = h2f(avs[k]);
      ax += a * b2f(v & 0xffffu);
      ay += a * b2fh(v);
    }
  }
  int nb = deg & 15;
  if (nb) {                                           // masked staged tail: 8 + optional 8
    int end1 = end - 1;
    {
      uint32 pks[8];
      unsigned short avs[8];
      #pragma unroll
      for (int k = 0; k < 8; ++k) {
        int jc = min(j0 + k, end1);
        pks[k] = packed[jc];
        avs[k] = att16[jc * 8 + hsel];
      }
      #pragma unroll
      for (int k = 0; k < 8; ++k) {
        uint32 v = fin2[(pks[k] & 0x3fffffu) | (uint32)lane];
        float a = h2f(avs[k]);
        a = (k < nb) ? a : 0.f;
        ax += a * b2f(v & 0xffffu);
        ay += a * b2fh(v);
      }
    }
    if (nb > 8) {
      uint32 pks[8];
      unsigned short avs[8];
      #pragma unroll
      for (int k = 0; k < 8; ++k) {
        int jc = min(j0 + 8 + k, end1);
        pks[k] = packed[jc];
        avs[k] = att16[jc * 8 + hsel];
      }
      #pragma unroll
      for (int k = 0; k < 8; ++k) {
        uint32 v = fin2[(pks[k] & 0x3fffffu) | (uint32)lane];
        float a = h2f(avs[k]);
        a = (8 + k < nb) ? a : 0.f;
        ax += a * b2f(v & 0xffffu);
        ay += a * b2fh(v);
      }
    }
  }
  float ox = 0.15f * b2f(z & 0xffffu) + 0.85f * ax;
  float oy = 0.15f * b2fh(z) + 0.85f * ay;
  if (!FINAL) {
    ((uint32*)fout)[n * 64 + lane] = ((uint32)f2b(oy) << 16) | (uint32)f2b(ox);
  } else {
    float x = ox + b2f(rz & 0xffffu);
    float y = oy + b2fh(rz);
    float s = x + y;
    #pragma unroll
    for (int o = 1; o < 64; o <<= 1) s += __shfl_xor(s, o);
    float mean = s * (1.f / 128.f);
    float dx = x - mean, dy = y - mean;
    float q = dx * dx + dy * dy;
    #pragma unroll
    for (int o = 1; o < 64; o <<= 1) q += __shfl_xor(q, o);
    float rs2 = rsqrtf(q * (1.f / 128.f) + 1e-5f);
    float2 gg = ((const float2*)g)[lane];
    float2 bb = ((const float2*)b)[lane];
    float o1 = dx * rs2 * gg.x + bb.x;
    float o2 = dy * rs2 * gg.y + bb.y;
    ((uint32*)fout)[n * 64 + lane] = ((uint32)f2b(o2) << 16) | (uint32)f2b(o1);
  }
}

// ---------------- final gather (fp32) ----------------
__global__ void k_gather(const int* __restrict__ ids, const float* __restrict__ h,
                         float* __restrict__ out) {
  int t = blockIdx.x * 256 + threadIdx.x;   // 512*32
  if (t >= 512 * 32) return;
  int b = t >> 5, c = t & 31;
  ((float4*)out)[t] = ((const float4*)h)[(long)ids[b] * 32 + c];
}

// ---------------- host side ----------------
struct LayerW {
  const float *Wh, *ah, *at, *g1, *b1, *w1, *c1, *w2, *c2, *g2, *b2;
};

extern "C" void kernel_launch(void* const* d_in, const int* in_sizes, int n_in,
                              void* d_out, int out_size, void* d_ws, size_t ws_size,
                              hipStream_t stream) {
  const int* ent_ids   = (const int*)d_in[0];
  const int* rel_ids   = (const int*)d_in[1];
  const int* arw_pos   = (const int*)d_in[2];
  const int* src       = (const int*)d_in[3];
  const int* dst       = (const int*)d_in[4];
  const int* batch_ids = (const int*)d_in[5];
  const float* ent_tab = (const float*)d_in[6];
  const float* rel_tab = (const float*)d_in[7];
  const float* pos_tab = (const float*)d_in[8];

  LayerW L0 = {(const float*)d_in[9],  (const float*)d_in[11], (const float*)d_in[12],
               (const float*)d_in[14], (const float*)d_in[15], (const float*)d_in[16],
               (const float*)d_in[17], (const float*)d_in[18], (const float*)d_in[19],
               (const float*)d_in[20], (const float*)d_in[21]};
  const float* l0_Wr = (const float*)d_in[10];
  const float* l0_ar = (const float*)d_in[13];
  LayerW L1 = {(const float*)d_in[22], (const float*)d_in[23], (const float*)d_in[24],
               (const float*)d_in[25], (const float*)d_in[26], (const float*)d_in[27],
               (const float*)d_in[28], (const float*)d_in[29], (const float*)d_in[30],
               (const float*)d_in[31], (const float*)d_in[32]};

  // ---- workspace carve ----
  char* p = (char*)d_ws;
  auto alloc = [&](size_t bytes) { char* q = p; p += (bytes + 255) & ~(size_t)255; return q; };
  __bf16* hb = (__bf16*)alloc((size_t)NP * 128 * 2);
  __bf16* f  = (__bf16*)alloc((size_t)NP * 128 * 2);
  __bf16* fb = (__bf16*)alloc((size_t)NP * 128 * 2);   // must follow f (y aliases f+fb)
  __bf16* fa = (__bf16*)alloc((size_t)NP * 128 * 2);
  __bf16* ob = (__bf16*)alloc((size_t)NP * 128 * 2);
  char*   U  = alloc((size_t)NP * 512 * 2);            // union: att16 (E*8 fp16) | T (bf16 NP*512)
  unsigned short* att16 = (unsigned short*)U;
  __bf16* T   = (__bf16*)U;
  float*  y   = (float*)f;                             // fp32 NP*128, spans f+fb
  float* ssrc  = (float*)alloc((size_t)NP * 8 * 4);
  float* sdst  = (float*)alloc((size_t)NP * 8 * 4);
  float* relsc = (float*)alloc(500 * 8 * 4);
  __bf16* Wht0 = (__bf16*)alloc(128 * 128 * 2);
  __bf16* Wht1 = (__bf16*)alloc(128 * 128 * 2);
  __bf16* w1t0 = (__bf16*)alloc(512 * 128 * 2);
  __bf16* w1t1 = (__bf16*)alloc(512 * 128 * 2);
  __bf16* w2t0 = (__bf16*)alloc(128 * 512 * 2);
  __bf16* w2t1 = (__bf16*)alloc(128 * 512 * 2);
  int* deg    = (int*)alloc(NNODES * 4);
  int* rowptr = (int*)alloc((NNODES + 1) * 4);
  int* cursor = (int*)alloc(NNODES * 4);
  int* csum   = (int*)alloc(64 * 4);
  uint32* packed = (uint32*)alloc((size_t)NEDGES * 4);

  // zero pads of GEMM A-inputs + degree array
  hipMemsetAsync(hb + (size_t)NNODES * 128, 0, (size_t)(NP - NNODES) * 128 * 2, stream);
  hipMemsetAsync(ob + (size_t)NNODES * 128, 0, (size_t)(NP - NNODES) * 128 * 2, stream);
  hipMemsetAsync(deg, 0, NNODES * sizeof(int), stream);

  k_embed_hist<<<EMB_B + HIST_B + TR_B + REL_B, 256, 0, stream>>>(
      ent_ids, arw_pos, ent_tab, pos_tab, hb, dst, deg,
      l0_Wr, l0_ar, rel_tab, relsc,
      L0.Wh, L1.Wh, L0.w1, L1.w1, L0.w2, L1.w2,
      Wht0, Wht1, w1t0, w1t1, w2t0, w2t1);
  k_prepA<<<49, 1024, 0, stream>>>(deg, csum);
  k_prepC<<<49, 1024, 0, stream>>>(deg, csum, rowptr, cursor);
  k_scatter<<<2048, 256, 0, stream>>>(dst, src, rel_ids, cursor, packed);

  const int NB4 = (NNODES + 3) / 4;
  for (int L = 0; L < 2; ++L) {
    const LayerW& W = L ? L1 : L0;
    const __bf16* Wht = L ? Wht1 : Wht0;
    const __bf16* w1t = L ? w1t1 : w1t0;
    const __bf16* w2t = L ? w2t1 : w2t0;
    const float* rsc  = L ? nullptr : relsc;

    k_gemm0s<<<391, 256, 0, stream>>>(hb, Wht, f, W.ah, W.at, ssrc, sdst);
    k_softmax<<<NB4, 256, 0, stream>>>(rowptr, packed, ssrc, sdst, rsc, att16);
    k_hop<0><<<NB4, 256, 0, stream>>>(rowptr, packed, att16, f, f, fa, nullptr, nullptr, nullptr);
    k_hop<0><<<NB4, 256, 0, stream>>>(rowptr, packed, att16, fa, f, fb, nullptr, nullptr, nullptr);
    k_hop<1><<<NB4, 256, 0, stream>>>(rowptr, packed, att16, fb, f, ob, hb, W.g1, W.b1);
    k_gemm<128, 512><<<dim3(391, 4), 256, 0, stream>>>(ob, w1t, W.c1, T);
    k_gemm2ln<<<391, 256, 0, stream>>>(T, w2t, W.c2, ob, W.g2, W.b2, hb,
                                       (L == 1) ? y : nullptr);
  }

  k_gather<<<64, 256, 0, stream>>>(batch_ids, y, (float*)d_out);
}

// Round 15
// 477.136 us; speedup vs baseline: 1.1030x; 1.0355x over previous
//
#include <hip/hip_runtime.h>
#include <hip/hip_bf16.h>

#define NNODES 50000
#define NEDGES 800000
#define NP 50048            // 391 * 128, padded node count
#define DIM 128
#define HEADS 8
#define FFNDIM 512

typedef __bf16 bf16x8 __attribute__((ext_vector_type(8)));
typedef float f32x4 __attribute__((ext_vector_type(4)));
typedef unsigned int uint32;
typedef unsigned short ushort16;

__device__ __forceinline__ float b2f(uint32 u) {
  union { uint32 i; float f; } x; x.i = u << 16; return x.f;
}
__device__ __forceinline__ float b2fh(uint32 u) {   // high half, no shift needed
  union { uint32 i; float f; } x; x.i = u & 0xffff0000u; return x.f;
}
__device__ __forceinline__ ushort16 f2b(float f) {
  __bf16 h = (__bf16)f; return __builtin_bit_cast(ushort16, h);
}
__device__ __forceinline__ float h2f(unsigned short u) {
  return (float)__builtin_bit_cast(_Float16, u);
}
__device__ __forceinline__ unsigned short f2h(float f) {
  return __builtin_bit_cast(unsigned short, (_Float16)f);
}

// ---------------- embed (blocks 0..1562, 8 threads/node) + partitioned hist (4096 blocks) ----------------
__global__ void k_embed_hist(const int* __restrict__ ent_ids, const int* __restrict__ arw_pos,
                             const float* __restrict__ ent_tab, const float* __restrict__ pos_tab,
                             __bf16* __restrict__ hb, const int* __restrict__ dst,
                             int* __restrict__ deg) {
  int bid = blockIdx.x, tid = threadIdx.x;
  if (bid < 1563) {
    int t = bid * 256 + tid;            // over N*8 (1563*256 = 400128 >= 400000)
    if (t < NNODES * 8) {
      int n = t >> 3, c = t & 7;
      int e = ent_ids[n], a2 = arw_pos[n];
      #pragma unroll
      for (int i = 0; i < 4; ++i) {
        float4 a0 = ((const float4*)ent_tab)[e * 32 + c * 4 + i];
        float4 b0 = ((const float4*)pos_tab)[a2 * 32 + c * 4 + i];
        ushort4 o;
        o.x = f2b(a0.x + b0.x); o.y = f2b(a0.y + b0.y);
        o.z = f2b(a0.z + b0.z); o.w = f2b(a0.w + b0.w);
        ((ushort4*)hb)[n * 32 + c * 4 + i] = o;
      }
    }
  } else {
    int hbid = bid - 1563;              // 0..4095
    int part = hbid & 7;
    int lo = part * 6250, hi2 = lo + 6250;
    for (int e = (hbid >> 3) * 256 + tid; e < NEDGES; e += 512 * 256) {
      int d = dst[e];
      if (d >= lo && d < hi2) atomicAdd(&deg[d], 1);
    }
  }
}

// ---------------- prepA: blocks 0..48 chunk sums; 49..52 relsc; 53..340 transpose ----------------
__global__ void k_prepA(const int* __restrict__ deg, int* __restrict__ csum,
                        const float* __restrict__ Wr, const float* __restrict__ ar,
                        const float* __restrict__ rel_tab, float* __restrict__ relsc,
                        const float* __restrict__ Wh0, const float* __restrict__ Wh1,
                        const float* __restrict__ w10, const float* __restrict__ w11,
                        const float* __restrict__ w20, const float* __restrict__ w21,
                        __bf16* __restrict__ T0, __bf16* __restrict__ T1,
                        __bf16* __restrict__ T2, __bf16* __restrict__ T3,
                        __bf16* __restrict__ T4, __bf16* __restrict__ T5) {
  int bid = blockIdx.x, tid = threadIdx.x;
  if (bid < 49) {
    __shared__ int ws[16];
    int lane = tid & 63, w = tid >> 6;
    int i = bid * 1024 + tid;
    int v = (i < NNODES) ? deg[i] : 0;
    #pragma unroll
    for (int o = 1; o < 64; o <<= 1) v += __shfl_xor(v, o);
    if (lane == 0) ws[w] = v;
    __syncthreads();
    if (tid == 0) {
      int s = 0;
      #pragma unroll
      for (int k = 0; k < 16; ++k) s += ws[k];
      csum[bid] = s;
    }
  } else if (bid <= 52) {
    __shared__ float vr[1024];
    int d = tid >> 3, hh = tid & 7;
    float s = 0.f;
    #pragma unroll
    for (int k = 0; k < 16; ++k) s += Wr[d * 128 + hh * 16 + k] * ar[hh * 16 + k];
    vr[tid] = s;
    __syncthreads();
    int t = (bid - 49) * 1024 + tid;
    if (t < 500 * 8) {
      int r = t >> 3, h2 = t & 7;
      float acc = 0.f;
      for (int dd = 0; dd < 128; ++dd) acc += rel_tab[r * 128 + dd] * vr[dd * 8 + h2];
      relsc[t] = acc;
    }
  } else {
    // transpose+convert, coalesced WRITES
    int wb = bid - 53;
    const float* W; __bf16* T; int lr2, lc2;
    int sub;
    if (wb < 16)        { W = Wh0; T = T0; lr2 = 7; lc2 = 7; sub = wb; }
    else if (wb < 32)   { W = Wh1; T = T1; lr2 = 7; lc2 = 7; sub = wb - 16; }
    else if (wb < 96)   { W = w10; T = T2; lr2 = 7; lc2 = 9; sub = wb - 32; }
    else if (wb < 160)  { W = w11; T = T3; lr2 = 7; lc2 = 9; sub = wb - 96; }
    else if (wb < 224)  { W = w20; T = T4; lr2 = 9; lc2 = 7; sub = wb - 160; }
    else                { W = w21; T = T5; lr2 = 9; lc2 = 7; sub = wb - 224; }
    int idx = sub * 1024 + tid;
    int r = idx & ((1 << lr2) - 1);
    int c = idx >> lr2;
    T[((long)c << lr2) + r] = (__bf16)W[((long)r << lc2) + c];
  }
}

// ---------------- prepC: per-chunk local scan + inline csum scan (49 blocks x 1024) ----------------
__global__ void k_prepC(const int* __restrict__ deg, const int* __restrict__ csum,
                        int* __restrict__ rowptr, int* __restrict__ cursor) {
  __shared__ int wsum[16];
  __shared__ int s_coff, s_tot;
  int tid = threadIdx.x, lane = tid & 63, w = tid >> 6;
  if (tid < 64) {
    int v = (tid < 49) ? csum[tid] : 0;
    int x = v;
    #pragma unroll
    for (int o = 1; o < 64; o <<= 1) {
      int t = __shfl_up(x, o);
      if (tid >= o) x += t;
    }
    if (tid == (int)blockIdx.x) s_coff = x - v;
    if (tid == 48) s_tot = x;
  }
  int i = blockIdx.x * 1024 + tid;
  int v = (i < NNODES) ? deg[i] : 0;
  int x = v;
  #pragma unroll
  for (int o = 1; o < 64; o <<= 1) {
    int t = __shfl_up(x, o);
    if (lane >= o) x += t;
  }
  if (lane == 63) wsum[w] = x;
  __syncthreads();
  if (w == 0 && lane < 16) {
    int t = wsum[lane];
    #pragma unroll
    for (int o = 1; o < 16; o <<= 1) {
      int u = __shfl_up(t, o);
      if (lane >= o) t += u;
    }
    wsum[lane] = t;
  }
  __syncthreads();
  int add = s_coff + (w > 0 ? wsum[w - 1] : 0);
  if (i < NNODES) { rowptr[i] = add + x - v; cursor[i] = add + x - v; }
  if (blockIdx.x == 0 && tid == 0) rowptr[NNODES] = s_tot;
}

// ---------------- partitioned scatter: pack (src<<6)|(rel<<22) into CSR slots ----------------
__global__ __launch_bounds__(256) void k_scatter(
    const int* __restrict__ dst, const int* __restrict__ src,
    const int* __restrict__ rel_ids, int* __restrict__ cursor,
    uint32* __restrict__ packed) {
  int part = blockIdx.x & 7;
  int lo = part * 6250, hi2 = lo + 6250;
  int tid = threadIdx.x;
  for (int e = (int)(blockIdx.x >> 3) * 256 + tid; e < NEDGES; e += 256 * 256) {
    int d = dst[e];
    if (d >= lo && d < hi2) {
      int p = atomicAdd(&cursor[d], 1);
      packed[p] = ((uint32)src[e] << 6) | ((uint32)rel_ids[e] << 22);
    }
  }
}

// ---------------- fused: f = hb@Wht (MFMA) + attention-scores epilogue ----------------
__global__ __launch_bounds__(256) void k_gemm0s(
    const __bf16* __restrict__ A, const __bf16* __restrict__ Bt,
    __bf16* __restrict__ fout, const float* __restrict__ ah, const float* __restrict__ at,
    float* __restrict__ ssrc, float* __restrict__ sdst) {
  __shared__ char sA[16384];   // 128 rows x 64 bf16, XOR-swizzled
  __shared__ char sB[16384];
  const int tid = threadIdx.x;
  const int lane = tid & 63, wid = tid >> 6;
  const int wr = wid >> 1, wc = wid & 1;
  const int lr = lane & 15, hi = lane >> 4;
  const long row0 = (long)blockIdx.x * 128;
  f32x4 acc[4][4] = {};

  for (int kc = 0; kc < 2; ++kc) {
    __syncthreads();
    #pragma unroll
    for (int i = 0; i < 4; ++i) {
      int q = i * 256 + tid;
      int r = q >> 3, slot = q & 7;
      int sw = ((slot ^ (r & 7)) << 4);
      int4 av = *(const int4*)(A + (row0 + r) * 128 + kc * 64 + slot * 8);
      *(int4*)(sA + r * 128 + sw) = av;
      int4 bv = *(const int4*)(Bt + (long)r * 128 + kc * 64 + slot * 8);
      *(int4*)(sB + r * 128 + sw) = bv;
    }
    __syncthreads();
    #pragma unroll
    for (int ks = 0; ks < 2; ++ks) {
      bf16x8 af[4], bfr[4];
      #pragma unroll
      for (int m = 0; m < 4; ++m) {
        int r = wr * 64 + m * 16 + lr;
        int cb = ((ks * 4 + hi) ^ (r & 7)) << 4;
        af[m] = *(const bf16x8*)(sA + r * 128 + cb);
      }
      #pragma unroll
      for (int n = 0; n < 4; ++n) {
        int r = wc * 64 + n * 16 + lr;
        int cb = ((ks * 4 + hi) ^ (r & 7)) << 4;
        bfr[n] = *(const bf16x8*)(sB + r * 128 + cb);
      }
      #pragma unroll
      for (int m = 0; m < 4; ++m)
        #pragma unroll
        for (int n = 0; n < 4; ++n)
          acc[m][n] = __builtin_amdgcn_mfma_f32_16x16x32_bf16(af[m], bfr[n], acc[m][n], 0, 0, 0);
    }
  }

  float ahr[4], atr[4];
  #pragma unroll
  for (int n = 0; n < 4; ++n) {
    ahr[n] = ah[(wc * 4 + n) * 16 + lr];
    atr[n] = at[(wc * 4 + n) * 16 + lr];
  }
  #pragma unroll
  for (int m = 0; m < 4; ++m) {
    #pragma unroll
    for (int j = 0; j < 4; ++j) {
      long r = row0 + wr * 64 + m * 16 + hi * 4 + j;
      #pragma unroll
      for (int n = 0; n < 4; ++n) {
        long c = wc * 64 + n * 16 + lr;
        float v = acc[m][n][j];
        fout[r * 128 + c] = (__bf16)v;
        float ps = v * ahr[n], pt = v * atr[n];
        #pragma unroll
        for (int o = 1; o < 16; o <<= 1) { ps += __shfl_xor(ps, o); pt += __shfl_xor(pt, o); }
        if (lr == 0) {
          ssrc[r * 8 + wc * 4 + n] = ps;
          sdst[r * 8 + wc * 4 + n] = pt;
        }
      }
    }
  }
}

// ---------------- FFN gemm1: T = relu(ob @ w1t + c1) ----------------
template<int KDIM, int NB>
__global__ __launch_bounds__(256) void k_gemm(
    const __bf16* __restrict__ A, const __bf16* __restrict__ Bt,
    const float* __restrict__ bias, __bf16* __restrict__ outb) {
  __shared__ char sA[16384];
  __shared__ char sB[16384];
  const int tid = threadIdx.x;
  const int lane = tid & 63, wid = tid >> 6;
  const int wr = wid >> 1, wc = wid & 1;
  const int lr = lane & 15, hi = lane >> 4;
  const long row0 = (long)blockIdx.x * 128;
  const long col0 = (long)blockIdx.y * 128;
  f32x4 acc[4][4] = {};

  for (int kc = 0; kc < KDIM / 64; ++kc) {
    __syncthreads();
    #pragma unroll
    for (int i = 0; i < 4; ++i) {
      int q = i * 256 + tid;
      int r = q >> 3, slot = q & 7;
      int sw = ((slot ^ (r & 7)) << 4);
      int4 av = *(const int4*)(A + (row0 + r) * KDIM + kc * 64 + slot * 8);
      *(int4*)(sA + r * 128 + sw) = av;
      int4 bv = *(const int4*)(Bt + (col0 + r) * KDIM + kc * 64 + slot * 8);
      *(int4*)(sB + r * 128 + sw) = bv;
    }
    __syncthreads();
    #pragma unroll
    for (int ks = 0; ks < 2; ++ks) {
      bf16x8 af[4], bfr[4];
      #pragma unroll
      for (int m = 0; m < 4; ++m) {
        int r = wr * 64 + m * 16 + lr;
        int cb = ((ks * 4 + hi) ^ (r & 7)) << 4;
        af[m] = *(const bf16x8*)(sA + r * 128 + cb);
      }
      #pragma unroll
      for (int n = 0; n < 4; ++n) {
        int r = wc * 64 + n * 16 + lr;
        int cb = ((ks * 4 + hi) ^ (r & 7)) << 4;
        bfr[n] = *(const bf16x8*)(sB + r * 128 + cb);
      }
      #pragma unroll
      for (int m = 0; m < 4; ++m)
        #pragma unroll
        for (int n = 0; n < 4; ++n)
          acc[m][n] = __builtin_amdgcn_mfma_f32_16x16x32_bf16(af[m], bfr[n], acc[m][n], 0, 0, 0);
    }
  }

  #pragma unroll
  for (int m = 0; m < 4; ++m) {
    #pragma unroll
    for (int j = 0; j < 4; ++j) {
      long r = row0 + wr * 64 + m * 16 + hi * 4 + j;
      #pragma unroll
      for (int n = 0; n < 4; ++n) {
        long c = col0 + wc * 64 + n * 16 + lr;
        outb[r * NB + c] = (__bf16)fmaxf(acc[m][n][j] + bias[c], 0.f);
      }
    }
  }
}

// ---------------- FFN gemm2 + residual + LayerNorm fused (full rows per block) ----------------
__global__ __launch_bounds__(256) void k_gemm2ln(
    const __bf16* __restrict__ A, const __bf16* __restrict__ Bt,
    const float* __restrict__ bias, const __bf16* __restrict__ resid,
    const float* __restrict__ g, const float* __restrict__ b,
    __bf16* __restrict__ outb, float* __restrict__ outf) {
  __shared__ char smem[65536];         // sA(16K)+sB(16K) during K-loop; fp32 V[128][128] after
  char* sA = smem;
  char* sB = smem + 16384;
  float* sV = (float*)smem;
  const int tid = threadIdx.x;
  const int lane = tid & 63, wid = tid >> 6;
  const int wr = wid >> 1, wc = wid & 1;
  const int lr = lane & 15, hi = lane >> 4;
  const long row0 = (long)blockIdx.x * 128;
  f32x4 acc[4][4] = {};

  for (int kc = 0; kc < 8; ++kc) {     // K = 512
    __syncthreads();
    #pragma unroll
    for (int i = 0; i < 4; ++i) {
      int q = i * 256 + tid;
      int r = q >> 3, slot = q & 7;
      int sw = ((slot ^ (r & 7)) << 4);
      int4 av = *(const int4*)(A + (row0 + r) * 512 + kc * 64 + slot * 8);
      *(int4*)(sA + r * 128 + sw) = av;
      int4 bv = *(const int4*)(Bt + (long)r * 512 + kc * 64 + slot * 8);
      *(int4*)(sB + r * 128 + sw) = bv;
    }
    __syncthreads();
    #pragma unroll
    for (int ks = 0; ks < 2; ++ks) {
      bf16x8 af[4], bfr[4];
      #pragma unroll
      for (int m = 0; m < 4; ++m) {
        int r = wr * 64 + m * 16 + lr;
        int cb = ((ks * 4 + hi) ^ (r & 7)) << 4;
        af[m] = *(const bf16x8*)(sA + r * 128 + cb);
      }
      #pragma unroll
      for (int n = 0; n < 4; ++n) {
        int r = wc * 64 + n * 16 + lr;
        int cb = ((ks * 4 + hi) ^ (r & 7)) << 4;
        bfr[n] = *(const bf16x8*)(sB + r * 128 + cb);
      }
      #pragma unroll
      for (int m = 0; m < 4; ++m)
        #pragma unroll
        for (int n = 0; n < 4; ++n)
          acc[m][n] = __builtin_amdgcn_mfma_f32_16x16x32_bf16(af[m], bfr[n], acc[m][n], 0, 0, 0);
    }
  }
  __syncthreads();                     // tiles dead; smem becomes V scratch

  float biasr[4];
  #pragma unroll
  for (int n = 0; n < 4; ++n) biasr[n] = bias[wc * 64 + n * 16 + lr];
  #pragma unroll
  for (int m = 0; m < 4; ++m) {
    #pragma unroll
    for (int j = 0; j < 4; ++j) {
      int rloc = wr * 64 + m * 16 + hi * 4 + j;
      long r = row0 + rloc;
      #pragma unroll
      for (int n = 0; n < 4; ++n) {
        int c = wc * 64 + n * 16 + lr;
        sV[rloc * 128 + c] = acc[m][n][j] + biasr[n] + (float)resid[r * 128 + c];
      }
    }
  }
  __syncthreads();

  float2 gg = ((const float2*)g)[lane];
  float2 bb = ((const float2*)b)[lane];
  for (int rr = 0; rr < 32; ++rr) {
    int rloc = wid * 32 + rr;
    long r = row0 + rloc;
    float2 v = ((float2*)sV)[rloc * 64 + lane];
    float x = v.x, y = v.y;
    float s = x + y;
    #pragma unroll
    for (int o = 1; o < 64; o <<= 1) s += __shfl_xor(s, o);
    float mean = s * (1.f / 128.f);
    float dx = x - mean, dy = y - mean;
    float q = dx * dx + dy * dy;
    #pragma unroll
    for (int o = 1; o < 64; o <<= 1) q += __shfl_xor(q, o);
    float rs = rsqrtf(q * (1.f / 128.f) + 1e-5f);
    float ox = dx * rs * gg.x + bb.x;
    float oy = dy * rs * gg.y + bb.y;
    if (outf) ((float2*)outf)[r * 64 + lane] = make_float2(ox, oy);
    ((uint32*)outb)[r * 64 + lane] = ((uint32)f2b(oy) << 16) | (uint32)f2b(ox);
  }
}

// ---------------- fused softmax + hop1: att from registers via shfl (deg<=64 fast path) ----------------
// softmax layout: lane=(jj=lane>>3, hh=lane&7); reg t holds edge t*8+jj, head hh.
// hop layout: lane covers feats 2*lane..2*lane+1, head hsel=lane>>3 (== jj).
// edge k -> reg t=k>>3, src lane ((k&7)<<3)+hsel.
__global__ __launch_bounds__(256) void k_softhop(
    const int* __restrict__ rowptr, const uint32* __restrict__ packed,
    const float* __restrict__ ssrc, const float* __restrict__ sdst,
    const float* __restrict__ relsc, unsigned short* __restrict__ att16,
    const __bf16* __restrict__ f, __bf16* __restrict__ fout) {
  int lane = threadIdx.x & 63, wid = threadIdx.x >> 6;
  int n = blockIdx.x * 4 + wid;
  if (n >= NNODES) return;
  uint32 z = ((const uint32*)f)[n * 64 + lane];       // f0 = f for hop1
  int start = rowptr[n], end = rowptr[n + 1];
  int deg = end - start;
  int hh = lane & 7, jj = lane >> 3;
  int hsel = jj;
  float ax = 0.f, ay = 0.f;
  const uint32* fin2 = (const uint32*)f;

  if (deg > 0 && deg <= 64) {
    float sd = sdst[n * 8 + hh];
    uint32 pk[8];
    float ev[8];
    int end1 = end - 1;
    #pragma unroll
    for (int t = 0; t < 8; ++t)
      pk[t] = packed[min(start + t * 8 + jj, end1)];
    #pragma unroll
    for (int t = 0; t < 8; ++t)
      ev[t] = ssrc[((pk[t] & 0x3fffffu) >> 3) | (uint32)hh];
    float m = -1e30f, den = 0.f;
    #pragma unroll
    for (int t = 0; t < 8; ++t) {
      float e = ev[t] + sd;
      if (relsc) e += relsc[((pk[t] >> 22) << 3) | (uint32)hh];
      e = (e >= 0.f) ? e : 0.2f * e;
      ev[t] = e;
      if (start + t * 8 + jj < end) {
        float M = fmaxf(m, e);
        den = den * __expf(m - M) + __expf(e - M);
        m = M;
      }
    }
    #pragma unroll
    for (int o = 8; o < 64; o <<= 1) {
      float m2 = __shfl_xor(m, o), d2 = __shfl_xor(den, o);
      float M = fmaxf(m, m2);
      den = den * __expf(m - M) + d2 * __expf(m2 - M);
      m = M;
    }
    float inv = 1.f / (den + 1e-16f);
    #pragma unroll
    for (int t = 0; t < 8; ++t) {
      ev[t] = __expf(ev[t] - m) * inv;                 // final att in regs (clamped slots harmless)
      int j = start + t * 8 + jj;
      if (j < end) att16[j * 8 + hh] = f2h(ev[t]);     // hops 2-3 read this
    }
    // hop1: 16 edges per step (2 register groups) -> 16 gathers in flight
    #pragma unroll
    for (int tb = 0; tb < 4; ++tb) {
      if (tb * 16 >= deg) break;
      #pragma unroll
      for (int i = 0; i < 16; ++i) {
        int k = tb * 16 + i;
        int t = tb * 2 + (i >> 3);
        int sl = ((i & 7) << 3) + hsel;
        float a = __shfl(ev[t], sl);
        a = (k < deg) ? a : 0.f;
        uint32 pkv = __shfl(pk[t], sl);
        uint32 v = fin2[(pkv & 0x3fffffu) | (uint32)lane];
        ax += a * b2f(v & 0xffffu);
        ay += a * b2fh(v);
      }
    }
  } else if (deg > 64) {
    // fallback: 2-pass softmax via att16, then generic hop1
    float sd = sdst[n * 8 + hh];
    float m = -1e30f, den = 0.f;
    for (int j0 = start; j0 < end; j0 += 8) {
      int j = j0 + jj;
      if (j < end) {
        uint32 p2 = packed[j];
        float e = ssrc[((p2 & 0x3fffffu) >> 3) | (uint32)hh] + sd;
        if (relsc) e += relsc[((p2 >> 22) << 3) | (uint32)hh];
        e = (e >= 0.f) ? e : 0.2f * e;
        att16[j * 8 + hh] = f2h(e);
        float M = fmaxf(m, e);
        den = den * __expf(m - M) + __expf(e - M);
        m = M;
      }
    }
    #pragma unroll
    for (int o = 8; o < 64; o <<= 1) {
      float m2 = __shfl_xor(m, o), d2 = __shfl_xor(den, o);
      float M = fmaxf(m, m2);
      den = den * __expf(m - M) + d2 * __expf(m2 - M);
      m = M;
    }
    float inv = 1.f / (den + 1e-16f);
    for (int j0 = start; j0 < end; j0 += 8) {
      int j = j0 + jj;
      if (j < end) att16[j * 8 + hh] = f2h(__expf(h2f(att16[j * 8 + hh]) - m) * inv);
    }
    // generic hop1 over att16 (all lanes in hop roles)
    for (int j = start; j < end; j += 16) {
      #pragma unroll
      for (int k = 0; k < 16; ++k) {
        int jc = min(j + k, end - 1);
        float a = h2f(att16[jc * 8 + hsel]);
        a = (j + k < end) ? a : 0.f;
        uint32 pkv = packed[jc];
        uint32 v = fin2[(pkv & 0x3fffffu) | (uint32)lane];
        ax += a * b2f(v & 0xffffu);
        ay += a * b2fh(v);
      }
    }
  }
  float ox = 0.15f * b2f(z & 0xffffu) + 0.85f * ax;
  float oy = 0.15f * b2fh(z) + 0.85f * ay;
  ((uint32*)fout)[n * 64 + lane] = ((uint32)f2b(oy) << 16) | (uint32)f2b(ox);
}

// ---------------- diffusion hop: register-staged batches (hops 2-3) ----------------
template<int FINAL>
__global__ __launch_bounds__(256) void k_hop(
    const int* __restrict__ rowptr, const uint32* __restrict__ packed,
    const unsigned short* __restrict__ att16, const __bf16* __restrict__ fin,
    const __bf16* __restrict__ f0, __bf16* __restrict__ fout,
    const __bf16* __restrict__ resid, const float* __restrict__ g,
    const float* __restrict__ b) {
  int lane = threadIdx.x & 63, wid = threadIdx.x >> 6;
  int n = blockIdx.x * 4 + wid;
  if (n >= NNODES) return;
  uint32 z = ((const uint32*)f0)[n * 64 + lane];
  uint32 rz = 0u;
  if (FINAL) rz = ((const uint32*)resid)[n * 64 + lane];
  int start = rowptr[n], end = rowptr[n + 1];
  int hsel = lane >> 3;
  float ax = 0.f, ay = 0.f;
  const uint32* fin2 = (const uint32*)fin;
  int deg = end - start;
  int nfull = deg >> 4;
  int j0 = start;
  for (int bb2 = 0; bb2 < nfull; ++bb2, j0 += 16) {   // full 16-edge batches, staged
    uint32 pks[16];
    unsigned short avs[16];
    #pragma unroll
    for (int k = 0; k < 16; ++k) pks[k] = packed[j0 + k];
    #pragma unroll
    for (int k = 0; k < 16; ++k) avs[k] = att16[(j0 + k) * 8 + hsel];
    #pragma unroll
    for (int k = 0; k < 16; ++k) {
      uint32 v = fin2[(pks[k] & 0x3fffffu) | (uint32)lane];
      float a = h2f(avs[k]);
      ax += a * b2f(v & 0xffffu);
      ay += a * b2fh(v);
    }
  }
  int nb = deg & 15;
  if (nb) {                                           // masked staged tail: 8 + optional 8
    int end1 = end - 1;
    {
      uint32 pks[8];
      unsigned short avs[8];
      #pragma unroll
      for (int k = 0; k < 8; ++k) {
        int jc = min(j0 + k, end1);
        pks[k] = packed[jc];
        avs[k] = att16[jc * 8 + hsel];
      }
      #pragma unroll
      for (int k = 0; k < 8; ++k) {
        uint32 v = fin2[(pks[k] & 0x3fffffu) | (uint32)lane];
        float a = h2f(avs[k]);
        a = (k < nb) ? a : 0.f;
        ax += a * b2f(v & 0xffffu);
        ay += a * b2fh(v);
      }
    }
    if (nb > 8) {
      uint32 pks[8];
      unsigned short avs[8];
      #pragma unroll
      for (int k = 0; k < 8; ++k) {
        int jc = min(j0 + 8 + k, end1);
        pks[k] = packed[jc];
        avs[k] = att16[jc * 8 + hsel];
      }
      #pragma unroll
      for (int k = 0; k < 8; ++k) {
        uint32 v = fin2[(pks[k] & 0x3fffffu) | (uint32)lane];
        float a = h2f(avs[k]);
        a = (8 + k < nb) ? a : 0.f;
        ax += a * b2f(v & 0xffffu);
        ay += a * b2fh(v);
      }
    }
  }
  float ox = 0.15f * b2f(z & 0xffffu) + 0.85f * ax;
  float oy = 0.15f * b2fh(z) + 0.85f * ay;
  if (!FINAL) {
    ((uint32*)fout)[n * 64 + lane] = ((uint32)f2b(oy) << 16) | (uint32)f2b(ox);
  } else {
    float x = ox + b2f(rz & 0xffffu);
    float y = oy + b2fh(rz);
    float s = x + y;
    #pragma unroll
    for (int o = 1; o < 64; o <<= 1) s += __shfl_xor(s, o);
    float mean = s * (1.f / 128.f);
    float dx = x - mean, dy = y - mean;
    float q = dx * dx + dy * dy;
    #pragma unroll
    for (int o = 1; o < 64; o <<= 1) q += __shfl_xor(q, o);
    float rs2 = rsqrtf(q * (1.f / 128.f) + 1e-5f);
    float2 gg = ((const float2*)g)[lane];
    float2 bb = ((const float2*)b)[lane];
    float o1 = dx * rs2 * gg.x + bb.x;
    float o2 = dy * rs2 * gg.y + bb.y;
    ((uint32*)fout)[n * 64 + lane] = ((uint32)f2b(o2) << 16) | (uint32)f2b(o1);
  }
}

// ---------------- final gather (fp32) ----------------
__global__ void k_gather(const int* __restrict__ ids, const float* __restrict__ h,
                         float* __restrict__ out) {
  int t = blockIdx.x * 256 + threadIdx.x;   // 512*32
  if (t >= 512 * 32) return;
  int b = t >> 5, c = t & 31;
  ((float4*)out)[t] = ((const float4*)h)[(long)ids[b] * 32 + c];
}

// ---------------- host side ----------------
struct LayerW {
  const float *Wh, *ah, *at, *g1, *b1, *w1, *c1, *w2, *c2, *g2, *b2;
};

extern "C" void kernel_launch(void* const* d_in, const int* in_sizes, int n_in,
                              void* d_out, int out_size, void* d_ws, size_t ws_size,
                              hipStream_t stream) {
  const int* ent_ids   = (const int*)d_in[0];
  const int* rel_ids   = (const int*)d_in[1];
  const int* arw_pos   = (const int*)d_in[2];
  const int* src       = (const int*)d_in[3];
  const int* dst       = (const int*)d_in[4];
  const int* batch_ids = (const int*)d_in[5];
  const float* ent_tab = (const float*)d_in[6];
  const float* rel_tab = (const float*)d_in[7];
  const float* pos_tab = (const float*)d_in[8];

  LayerW L0 = {(const float*)d_in[9],  (const float*)d_in[11], (const float*)d_in[12],
               (const float*)d_in[14], (const float*)d_in[15], (const float*)d_in[16],
               (const float*)d_in[17], (const float*)d_in[18], (const float*)d_in[19],
               (const float*)d_in[20], (const float*)d_in[21]};
  const float* l0_Wr = (const float*)d_in[10];
  const float* l0_ar = (const float*)d_in[13];
  LayerW L1 = {(const float*)d_in[22], (const float*)d_in[23], (const float*)d_in[24],
               (const float*)d_in[25], (const float*)d_in[26], (const float*)d_in[27],
               (const float*)d_in[28], (const float*)d_in[29], (const float*)d_in[30],
               (const float*)d_in[31], (const float*)d_in[32]};

  // ---- workspace carve ----
  char* p = (char*)d_ws;
  auto alloc = [&](size_t bytes) { char* q = p; p += (bytes + 255) & ~(size_t)255; return q; };
  __bf16* hb = (__bf16*)alloc((size_t)NP * 128 * 2);
  __bf16* f  = (__bf16*)alloc((size_t)NP * 128 * 2);
  __bf16* fb = (__bf16*)alloc((size_t)NP * 128 * 2);   // must follow f (y aliases f+fb)
  __bf16* fa = (__bf16*)alloc((size_t)NP * 128 * 2);
  __bf16* ob = (__bf16*)alloc((size_t)NP * 128 * 2);
  char*   U  = alloc((size_t)NP * 512 * 2);            // union: att16 (E*8 fp16) | T (bf16 NP*512)
  unsigned short* att16 = (unsigned short*)U;
  __bf16* T   = (__bf16*)U;
  float*  y   = (float*)f;                             // fp32 NP*128, spans f+fb
  float* ssrc  = (float*)alloc((size_t)NP * 8 * 4);
  float* sdst  = (float*)alloc((size_t)NP * 8 * 4);
  float* relsc = (float*)alloc(500 * 8 * 4);
  __bf16* Wht0 = (__bf16*)alloc(128 * 128 * 2);
  __bf16* Wht1 = (__bf16*)alloc(128 * 128 * 2);
  __bf16* w1t0 = (__bf16*)alloc(512 * 128 * 2);
  __bf16* w1t1 = (__bf16*)alloc(512 * 128 * 2);
  __bf16* w2t0 = (__bf16*)alloc(128 * 512 * 2);
  __bf16* w2t1 = (__bf16*)alloc(128 * 512 * 2);
  int* deg    = (int*)alloc(NNODES * 4);
  int* rowptr = (int*)alloc((NNODES + 1) * 4);
  int* cursor = (int*)alloc(NNODES * 4);
  int* csum   = (int*)alloc(64 * 4);
  uint32* packed = (uint32*)alloc((size_t)NEDGES * 4);

  // zero pads of GEMM A-inputs + degree array
  hipMemsetAsync(hb + (size_t)NNODES * 128, 0, (size_t)(NP - NNODES) * 128 * 2, stream);
  hipMemsetAsync(ob + (size_t)NNODES * 128, 0, (size_t)(NP - NNODES) * 128 * 2, stream);
  hipMemsetAsync(deg, 0, NNODES * sizeof(int), stream);

  k_embed_hist<<<1563 + 4096, 256, 0, stream>>>(ent_ids, arw_pos, ent_tab, pos_tab, hb, dst, deg);
  k_prepA<<<341, 1024, 0, stream>>>(deg, csum, l0_Wr, l0_ar, rel_tab, relsc,
                                    L0.Wh, L1.Wh, L0.w1, L1.w1, L0.w2, L1.w2,
                                    Wht0, Wht1, w1t0, w1t1, w2t0, w2t1);
  k_prepC<<<49, 1024, 0, stream>>>(deg, csum, rowptr, cursor);
  k_scatter<<<2048, 256, 0, stream>>>(dst, src, rel_ids, cursor, packed);

  const int NB4 = (NNODES + 3) / 4;
  for (int L = 0; L < 2; ++L) {
    const LayerW& W = L ? L1 : L0;
    const __bf16* Wht = L ? Wht1 : Wht0;
    const __bf16* w1t = L ? w1t1 : w1t0;
    const __bf16* w2t = L ? w2t1 : w2t0;
    const float* rsc  = L ? nullptr : relsc;

    k_gemm0s<<<391, 256, 0, stream>>>(hb, Wht, f, W.ah, W.at, ssrc, sdst);
    k_softhop<<<NB4, 256, 0, stream>>>(rowptr, packed, ssrc, sdst, rsc, att16, f, fa);
    k_hop<0><<<NB4, 256, 0, stream>>>(rowptr, packed, att16, fa, f, fb, nullptr, nullptr, nullptr);
    k_hop<1><<<NB4, 256, 0, stream>>>(rowptr, packed, att16, fb, f, ob, hb, W.g1, W.b1);
    k_gemm<128, 512><<<dim3(391, 4), 256, 0, stream>>>(ob, w1t, W.c1, T);
    k_gemm2ln<<<391, 256, 0, stream>>>(T, w2t, W.c2, ob, W.g2, W.b2, hb,
                                       (L == 1) ? y : nullptr);
  }

  k_gather<<<64, 256, 0, stream>>>(batch_ids, y, (float*)d_out);
}